// Round 1
// baseline (3493.241 us; speedup 1.0000x reference)
//
#include <hip/hip_runtime.h>
#include <math.h>

#define NRES 50000
#define NEDGE 1000000
#define PI_F 3.14159265358979323846f

struct f3 { float x, y, z; };
__device__ __forceinline__ f3 ld3(const float* __restrict__ p, int i) {
  return {p[3*i+0], p[3*i+1], p[3*i+2]};
}
__device__ __forceinline__ f3 f3sub(f3 a, f3 b){ return {a.x-b.x, a.y-b.y, a.z-b.z}; }
__device__ __forceinline__ f3 f3cross(f3 a, f3 b){
  return {a.y*b.z - a.z*b.y, a.z*b.x - a.x*b.z, a.x*b.y - a.y*b.x};
}
__device__ __forceinline__ float f3dot(f3 a, f3 b){ return a.x*b.x + a.y*b.y + a.z*b.z; }
__device__ __forceinline__ float f3norm(f3 a){ return sqrtf(f3dot(a,a)); }
__device__ __forceinline__ float sigmoidf(float v){ return 1.0f/(1.0f + expf(-v)); }
__device__ __forceinline__ float swishf(float v){ return v * sigmoidf(v); }

// ---------------------------------------------------------------------------
// x_a: [oh(26)|bb(6)|side(8)] @ W_emb[40,64] + b_emb  -> x[:, 0:64]
// one thread per (node, channel); 4 nodes / 256-thread block
__global__ __launch_bounds__(256) void k_xa(
    const int* __restrict__ z, const float* __restrict__ bb,
    const float* __restrict__ side, const float* __restrict__ W_emb,
    const float* __restrict__ b_emb, float* __restrict__ x)
{
  int tid = threadIdx.x;
  int h = tid & 63;
  int n = blockIdx.x * 4 + (tid >> 6);
  if (n >= NRES) return;
  int zz = z[n];
  float acc = W_emb[zz * 64 + h] + b_emb[h];
  #pragma unroll
  for (int k = 0; k < 6; ++k) acc += bb[n*6 + k] * W_emb[(26 + k)*64 + h];
  #pragma unroll
  for (int k = 0; k < 8; ++k) acc += side[n*8 + k] * W_emb[(32 + k)*64 + h];
  x[(size_t)n * 128 + h] = acc;
}

// ---------------------------------------------------------------------------
// x_s: esm[50000,1280] @ W_esm[1280,64] + b_esm -> x[:, 64:128]
// tiled GEMM: BM=64, BN=64, BK=32, 256 threads, 4x4 micro-tile, A transposed in LDS
__global__ __launch_bounds__(256) void k_esm(
    const float* __restrict__ esm, const float* __restrict__ W,
    const float* __restrict__ b, float* __restrict__ x)
{
  __shared__ __align__(16) float sA[32][68];   // A^T: sA[k][n]
  __shared__ __align__(16) float sB[32][64];   // sB[k][c]
  const int tid = threadIdx.x;
  const int tx = tid & 15, ty = tid >> 4;      // 16 x 16
  const int n0 = blockIdx.x * 64;

  float acc[4][4];
  #pragma unroll
  for (int u = 0; u < 4; ++u)
    #pragma unroll
    for (int v = 0; v < 4; ++v) acc[u][v] = 0.0f;

  for (int kt = 0; kt < 40; ++kt) {
    int k0 = kt * 32;
    #pragma unroll
    for (int p = 0; p < 2; ++p) {
      int idx = p * 256 + tid;          // 0..511
      int nl = idx >> 3;                // 0..63
      int kc = (idx & 7) << 2;          // 0..28
      int n = n0 + nl;
      float4 v = make_float4(0.f, 0.f, 0.f, 0.f);
      if (n < NRES) v = *(const float4*)&esm[(size_t)n * 1280 + k0 + kc];
      sA[kc + 0][nl] = v.x; sA[kc + 1][nl] = v.y;
      sA[kc + 2][nl] = v.z; sA[kc + 3][nl] = v.w;
      int kl = idx >> 4;                // 0..31
      int c = (idx & 15) << 2;          // 0..60
      *(float4*)&sB[kl][c] = *(const float4*)&W[(size_t)(k0 + kl) * 64 + c];
    }
    __syncthreads();
    #pragma unroll
    for (int kk = 0; kk < 32; ++kk) {
      float4 a4 = *(const float4*)&sA[kk][4 * ty];
      float4 b4 = *(const float4*)&sB[kk][4 * tx];
      float av[4] = {a4.x, a4.y, a4.z, a4.w};
      float bv[4] = {b4.x, b4.y, b4.z, b4.w};
      #pragma unroll
      for (int u = 0; u < 4; ++u)
        #pragma unroll
        for (int v = 0; v < 4; ++v) acc[u][v] += av[u] * bv[v];
    }
    __syncthreads();
  }
  float4 bias = *(const float4*)&b[4 * tx];
  float bv[4] = {bias.x, bias.y, bias.z, bias.w};
  #pragma unroll
  for (int u = 0; u < 4; ++u) {
    int n = n0 + 4 * ty + u;
    if (n < NRES) {
      float4 o;
      o.x = acc[u][0] + bv[0]; o.y = acc[u][1] + bv[1];
      o.z = acc[u][2] + bv[2]; o.w = acc[u][3] + bv[3];
      *(float4*)&x[(size_t)n * 128 + 64 + 4 * tx] = o;
    }
  }
}

// ---------------------------------------------------------------------------
// node head: node_out = relu(x @ W_n0 + b_n0) @ W_nf + b_nf   (uses x, not xe)
// 8 nodes per 256-thread block; thread = (node, ch<32)
__global__ __launch_bounds__(256) void k_nodehead(
    const float* __restrict__ x, const float* __restrict__ Wn0,
    const float* __restrict__ bn0, const float* __restrict__ Wnf,
    const float* __restrict__ bnf, float* __restrict__ out1)
{
  __shared__ float sXN[8][36];
  int tid = threadIdx.x;
  int nl = tid >> 5, ch = tid & 31;
  int n = blockIdx.x * 8 + nl;     // grid exact: 6250*8 = 50000
  const float* xr = &x[(size_t)n * 128];
  float a = bn0[ch];
  for (int k = 0; k < 128; ++k) a += xr[k] * Wn0[k * 32 + ch];
  sXN[nl][ch] = fmaxf(a, 0.0f);
  __syncthreads();
  if (tid < 16) {
    int nl2 = tid >> 1, oc = tid & 1;
    int nn = blockIdx.x * 8 + nl2;
    float a2 = bnf[oc];
    #pragma unroll
    for (int k = 0; k < 32; ++k) a2 += sXN[nl2][k] * Wnf[k * 2 + oc];
    out1[(size_t)nn * 2 + oc] = a2;
  }
}

// ---------------------------------------------------------------------------
// edge kernel: geometry -> f[124]; ef = swish(f@W_edge); m = swish(x[j]@W_msg)*ef;
// atomicAdd into agg[i]. 32 edges / 128-thread block.
__global__ __launch_bounds__(128) void k_edge(
    const int* __restrict__ ei, const float* __restrict__ pos,
    const float* __restrict__ posn, const float* __restrict__ posc,
    const float* __restrict__ x, const float* __restrict__ We,
    const float* __restrict__ Wm, float* __restrict__ agg)
{
  __shared__ int sJ[32];
  __shared__ int sI[32];
  __shared__ __align__(16) float sF[32][132];    // edge features, cols 124..131 = 0
  __shared__ __align__(16) float sXJ[32][132];   // gathered x[j] rows (128 cols used)
  __shared__ __align__(16) float sWe[16][128];
  __shared__ __align__(16) float sWm[16][128];

  const int tid = threadIdx.x;
  const int e0 = blockIdx.x * 32;

  if (tid < 32) { sJ[tid] = ei[e0 + tid]; sI[tid] = ei[NEDGE + e0 + tid]; }
  __syncthreads();

  if (tid < 32) {
    const int e = tid;
    const int j = sJ[e], i = sI[e];
    f3 pj = ld3(pos, j), pi = ld3(pos, i);
    f3 vji = f3sub(pj, pi);
    float dist = f3norm(vji);
    int r0i = (i == 0) ? (NRES - 1) : (i - 1);
    int r1i = (i == NRES - 1) ? 0 : (i + 1);
    f3 vr0 = f3sub(ld3(pos, r0i), pi);
    f3 vr1 = f3sub(ld3(pos, r1i), pi);
    float ta = f3dot(vji, vr0);
    float tb = f3norm(f3cross(vji, vr0));
    float theta = atan2f(tb, ta);
    f3 p1 = f3cross(vr0, vr1);
    f3 p2 = f3cross(vr0, vji);
    float pa = f3dot(p1, p2);
    float pb = f3dot(f3cross(p1, p2), vr0) / (f3norm(vr0) + 1e-7f);
    float phi = atan2f(pb, pa);

    f3 pni = ld3(posn, i), pci = ld3(posc, i);
    f3 o1x = f3sub(pni, pi);
    f3 o1z = f3cross(o1x, f3cross(o1x, f3sub(pci, pi)));
    float o1zl = f3norm(o1z) + 1e-7f;
    f3 pnj = ld3(posn, j), pcj = ld3(posc, j);
    f3 o2x = f3sub(pnj, pj);
    f3 o2z = f3cross(o2x, f3cross(o2x, f3sub(pcj, pj)));
    float o2zl = f3norm(o2z) + 1e-7f;
    f3 nv = f3cross(o1z, o2z);
    float an1 = atan2f(f3dot(f3cross(o1x, nv), o1z) / o1zl, f3dot(o1x, nv));
    float an2 = atan2f(f3norm(nv), f3dot(o1z, o2z));
    float an3 = atan2f(f3dot(f3cross(nv, o2x), o2z) / o2zl, f3dot(nv, o2x));

    // shared radial basis (Bessel + cosine cutoff)
    float u = fminf(dist / 11.5f, 1.0f);
    float fc = 0.5f * (cosf(PI_F * u) + 1.0f);
    float pref = 0.41702882811414954f / (dist + 1e-6f) * fc;  // sqrt(2/11.5)
    float rb[6];
    #pragma unroll
    for (int nn = 0; nn < 6; ++nn) rb[nn] = pref * sinf((float)(nn + 1) * PI_F * u);

    // feature0: r (x) cos(l*theta) (x) cos(m*phi), idx n*9 + l*3 + m
    float ctv[3] = {1.0f, cosf(theta), cosf(2.0f * theta)};
    float cpv[3] = {1.0f, cosf(phi),   cosf(2.0f * phi)};
    #pragma unroll
    for (int nn = 0; nn < 6; ++nn)
      #pragma unroll
      for (int l = 0; l < 3; ++l)
        #pragma unroll
        for (int m = 0; m < 3; ++m)
          sF[e][nn*9 + l*3 + m] = rb[nn] * ctv[l] * cpv[m];

    // feature1: three angle_embs, idx 54 + t*18 + n*3 + l
    float angs[3] = {an1, an2, an3};
    #pragma unroll
    for (int t = 0; t < 3; ++t) {
      float cav[3] = {1.0f, cosf(angs[t]), cosf(2.0f * angs[t])};
      #pragma unroll
      for (int nn = 0; nn < 6; ++nn)
        #pragma unroll
        for (int l = 0; l < 3; ++l)
          sF[e][54 + t*18 + nn*3 + l] = rb[nn] * cav[l];
    }

    // positional embedding: cos/sin(dpe * 10^{-q/2}), idx 108+q / 116+q
    const float FRQ[8] = {1.0f, 0.31622776601683794f, 0.1f, 0.03162277660168379f,
                          0.01f, 0.003162277660168379f, 0.001f, 0.0003162277660168379f};
    float dpe = (float)(j - i);
    #pragma unroll
    for (int q = 0; q < 8; ++q) {
      float s, c;
      sincosf(dpe * FRQ[q], &s, &c);
      sF[e][108 + q] = c;
      sF[e][116 + q] = s;
    }
    #pragma unroll
    for (int k = 124; k < 132; ++k) sF[e][k] = 0.0f;
  } else {
    // threads 32..127 gather x[j] rows (32 rows x 32 float4 = 1024 float4)
    const int t2 = tid - 32;
    for (int it = 0; it < 11; ++it) {
      int idx = it * 96 + t2;
      if (idx < 1024) {
        int row = idx >> 5;
        int c = (idx & 31) << 2;
        *(float4*)&sXJ[row][c] = *(const float4*)&x[(size_t)sJ[row] * 128 + c];
      }
    }
  }
  __syncthreads();

  // dual GEMM: [32 edges] x [128 ch], K=128 (F zero-padded), BK=16 weight staging
  const int tx = tid & 15, ty = tid >> 4;  // tx 0..15 (ch/4), ty 0..7 (edge/4)
  float acc_e[4][8], acc_m[4][8];
  #pragma unroll
  for (int u = 0; u < 4; ++u)
    #pragma unroll
    for (int v = 0; v < 8; ++v) { acc_e[u][v] = 0.0f; acc_m[u][v] = 0.0f; }

  for (int kt = 0; kt < 8; ++kt) {
    #pragma unroll
    for (int it = 0; it < 4; ++it) {
      int idx = it * 128 + tid;           // 0..511
      int k = idx >> 5;                   // 0..15
      int c = (idx & 31) << 2;            // 0..124
      int gk = kt * 16 + k;
      float4 ve = make_float4(0.f, 0.f, 0.f, 0.f);
      if (gk < 124) ve = *(const float4*)&We[(size_t)gk * 128 + c];
      *(float4*)&sWe[k][c] = ve;
      *(float4*)&sWm[k][c] = *(const float4*)&Wm[(size_t)gk * 128 + c];
    }
    __syncthreads();
    #pragma unroll
    for (int kk = 0; kk < 16; ++kk) {
      int gk = kt * 16 + kk;
      float af[4], ax[4];
      #pragma unroll
      for (int u = 0; u < 4; ++u) {
        af[u] = sF[4*ty + u][gk];
        ax[u] = sXJ[4*ty + u][gk];
      }
      float4 we0 = *(const float4*)&sWe[kk][4*tx];
      float4 we1 = *(const float4*)&sWe[kk][64 + 4*tx];
      float4 wm0 = *(const float4*)&sWm[kk][4*tx];
      float4 wm1 = *(const float4*)&sWm[kk][64 + 4*tx];
      #pragma unroll
      for (int u = 0; u < 4; ++u) {
        acc_e[u][0] += af[u]*we0.x; acc_e[u][1] += af[u]*we0.y;
        acc_e[u][2] += af[u]*we0.z; acc_e[u][3] += af[u]*we0.w;
        acc_e[u][4] += af[u]*we1.x; acc_e[u][5] += af[u]*we1.y;
        acc_e[u][6] += af[u]*we1.z; acc_e[u][7] += af[u]*we1.w;
        acc_m[u][0] += ax[u]*wm0.x; acc_m[u][1] += ax[u]*wm0.y;
        acc_m[u][2] += ax[u]*wm0.z; acc_m[u][3] += ax[u]*wm0.w;
        acc_m[u][4] += ax[u]*wm1.x; acc_m[u][5] += ax[u]*wm1.y;
        acc_m[u][6] += ax[u]*wm1.z; acc_m[u][7] += ax[u]*wm1.w;
      }
    }
    __syncthreads();
  }

  // m = swish(x[j]@Wm) * swish(f@We); scatter-add to agg[i]
  #pragma unroll
  for (int u = 0; u < 4; ++u) {
    int le = 4*ty + u;
    int idst = sI[le];
    float* arow = agg + (size_t)idst * 128;
    #pragma unroll
    for (int v = 0; v < 8; ++v) {
      int ch = (v < 4) ? (4*tx + v) : (64 + 4*tx + (v - 4));
      float m = swishf(acc_m[u][v]) * swishf(acc_e[u][v]);
      atomicAdd(arow + ch, m);
    }
  }
}

// ---------------------------------------------------------------------------
// update + out head: xe = x + swish(agg@W_upd); h = relu(xe@W_o0+b);
// h2 = relu(h@W_o1+b); out = sigmoid(h2@W_of+b). 32 nodes / 128-thread block.
__global__ __launch_bounds__(128) void k_upd(
    const float* __restrict__ x, const float* __restrict__ agg,
    const float* __restrict__ Wu, const float* __restrict__ Wo0,
    const float* __restrict__ bo0, const float* __restrict__ Wo1,
    const float* __restrict__ bo1, const float* __restrict__ Wof,
    const float* __restrict__ bof, float* __restrict__ out)
{
  __shared__ __align__(16) float sIn[32][132];
  __shared__ __align__(16) float sXE[32][132];
  __shared__ __align__(16) float sH[32][132];
  __shared__ __align__(16) float sW[16][128];
  __shared__ __align__(16) float sH2[32][36];

  const int tid = threadIdx.x;
  const int tx = tid & 15, ty = tid >> 4;   // tx 0..15, ty 0..7
  const int n0 = blockIdx.x * 32;

  #pragma unroll
  for (int it = 0; it < 8; ++it) {
    int idx = it * 128 + tid;
    int row = idx >> 5, c = (idx & 31) << 2;
    int n = n0 + row;
    float4 v = make_float4(0.f, 0.f, 0.f, 0.f);
    if (n < NRES) v = *(const float4*)&agg[(size_t)n * 128 + c];
    *(float4*)&sIn[row][c] = v;
  }
  __syncthreads();

  // GEMM1: T = agg_tile @ W_upd
  float acc[4][8];
  #pragma unroll
  for (int u = 0; u < 4; ++u)
    #pragma unroll
    for (int v = 0; v < 8; ++v) acc[u][v] = 0.0f;

  for (int kt = 0; kt < 8; ++kt) {
    #pragma unroll
    for (int it = 0; it < 4; ++it) {
      int idx = it * 128 + tid;
      int k = idx >> 5, c = (idx & 31) << 2;
      *(float4*)&sW[k][c] = *(const float4*)&Wu[(size_t)(kt*16 + k) * 128 + c];
    }
    __syncthreads();
    #pragma unroll
    for (int kk = 0; kk < 16; ++kk) {
      int gk = kt * 16 + kk;
      float a[4];
      #pragma unroll
      for (int u = 0; u < 4; ++u) a[u] = sIn[4*ty + u][gk];
      float4 w0 = *(const float4*)&sW[kk][4*tx];
      float4 w1 = *(const float4*)&sW[kk][64 + 4*tx];
      #pragma unroll
      for (int u = 0; u < 4; ++u) {
        acc[u][0] += a[u]*w0.x; acc[u][1] += a[u]*w0.y;
        acc[u][2] += a[u]*w0.z; acc[u][3] += a[u]*w0.w;
        acc[u][4] += a[u]*w1.x; acc[u][5] += a[u]*w1.y;
        acc[u][6] += a[u]*w1.z; acc[u][7] += a[u]*w1.w;
      }
    }
    __syncthreads();
  }
  // xe = x + swish(T)
  #pragma unroll
  for (int u = 0; u < 4; ++u) {
    int row = 4*ty + u;
    int n = n0 + row;
    #pragma unroll
    for (int cb = 0; cb < 2; ++cb) {
      int ch = cb*64 + 4*tx;
      float4 xv = make_float4(0.f, 0.f, 0.f, 0.f);
      if (n < NRES) xv = *(const float4*)&x[(size_t)n * 128 + ch];
      float4 o;
      o.x = xv.x + swishf(acc[u][cb*4 + 0]);
      o.y = xv.y + swishf(acc[u][cb*4 + 1]);
      o.z = xv.z + swishf(acc[u][cb*4 + 2]);
      o.w = xv.w + swishf(acc[u][cb*4 + 3]);
      *(float4*)&sXE[row][ch] = o;
    }
  }
  __syncthreads();

  // GEMM2: H = relu(xe @ W_o0 + b_o0)
  float acc2[4][8];
  #pragma unroll
  for (int u = 0; u < 4; ++u)
    #pragma unroll
    for (int v = 0; v < 8; ++v) acc2[u][v] = 0.0f;

  for (int kt = 0; kt < 8; ++kt) {
    #pragma unroll
    for (int it = 0; it < 4; ++it) {
      int idx = it * 128 + tid;
      int k = idx >> 5, c = (idx & 31) << 2;
      *(float4*)&sW[k][c] = *(const float4*)&Wo0[(size_t)(kt*16 + k) * 128 + c];
    }
    __syncthreads();
    #pragma unroll
    for (int kk = 0; kk < 16; ++kk) {
      int gk = kt * 16 + kk;
      float a[4];
      #pragma unroll
      for (int u = 0; u < 4; ++u) a[u] = sXE[4*ty + u][gk];
      float4 w0 = *(const float4*)&sW[kk][4*tx];
      float4 w1 = *(const float4*)&sW[kk][64 + 4*tx];
      #pragma unroll
      for (int u = 0; u < 4; ++u) {
        acc2[u][0] += a[u]*w0.x; acc2[u][1] += a[u]*w0.y;
        acc2[u][2] += a[u]*w0.z; acc2[u][3] += a[u]*w0.w;
        acc2[u][4] += a[u]*w1.x; acc2[u][5] += a[u]*w1.y;
        acc2[u][6] += a[u]*w1.z; acc2[u][7] += a[u]*w1.w;
      }
    }
    __syncthreads();
  }
  {
    float4 b0 = *(const float4*)&bo0[4*tx];
    float4 b1 = *(const float4*)&bo0[64 + 4*tx];
    float bb0[4] = {b0.x, b0.y, b0.z, b0.w};
    float bb1[4] = {b1.x, b1.y, b1.z, b1.w};
    #pragma unroll
    for (int u = 0; u < 4; ++u) {
      int row = 4*ty + u;
      #pragma unroll
      for (int v = 0; v < 4; ++v) {
        sH[row][4*tx + v]      = fmaxf(acc2[u][v]     + bb0[v], 0.0f);
        sH[row][64 + 4*tx + v] = fmaxf(acc2[u][4 + v] + bb1[v], 0.0f);
      }
    }
  }
  __syncthreads();

  // GEMM3: H2 = relu(H @ W_o1 + b_o1), [32 x 32]
  {
    int ch = tid & 31, rp = tid >> 5;   // 4 rows per pass
    #pragma unroll
    for (int p = 0; p < 8; ++p) {
      int row = p * 4 + rp;
      float a = bo1[ch];
      for (int k = 0; k < 128; ++k) a += sH[row][k] * Wo1[k * 32 + ch];
      sH2[row][ch] = fmaxf(a, 0.0f);
    }
  }
  __syncthreads();

  if (tid < 32) {
    int n = n0 + tid;
    if (n < NRES) {
      float a = bof[0];
      #pragma unroll
      for (int k = 0; k < 32; ++k) a += sH2[tid][k] * Wof[k];
      out[n] = sigmoidf(a);
    }
  }
}

// ---------------------------------------------------------------------------
extern "C" void kernel_launch(void* const* d_in, const int* in_sizes, int n_in,
                              void* d_out, int out_size, void* d_ws, size_t ws_size,
                              hipStream_t stream) {
  (void)in_sizes; (void)n_in; (void)out_size; (void)ws_size;
  const int*   z     = (const int*)  d_in[0];
  const float* pos   = (const float*)d_in[1];
  const float* posn  = (const float*)d_in[2];
  const float* posc  = (const float*)d_in[3];
  const float* bb    = (const float*)d_in[4];
  const float* side  = (const float*)d_in[5];
  const float* esm   = (const float*)d_in[6];
  // d_in[7] = batch (unused)
  const int*   ei    = (const int*)  d_in[8];
  const float* W_emb = (const float*)d_in[9];
  const float* b_emb = (const float*)d_in[10];
  const float* W_esm = (const float*)d_in[11];
  const float* b_esm = (const float*)d_in[12];
  const float* W_edge= (const float*)d_in[13];
  const float* W_msg = (const float*)d_in[14];
  const float* W_upd = (const float*)d_in[15];
  const float* W_o0  = (const float*)d_in[16];
  const float* b_o0  = (const float*)d_in[17];
  const float* W_o1  = (const float*)d_in[18];
  const float* b_o1  = (const float*)d_in[19];
  const float* W_of  = (const float*)d_in[20];
  const float* b_of  = (const float*)d_in[21];
  const float* W_n0  = (const float*)d_in[22];
  const float* b_n0  = (const float*)d_in[23];
  const float* W_nf  = (const float*)d_in[24];
  const float* b_nf  = (const float*)d_in[25];

  float* x    = (float*)d_ws;                  // [N,128]  25.6 MB
  float* agg  = x + (size_t)NRES * 128;        // [N,128]  25.6 MB
  float* out0 = (float*)d_out;                 // [N]
  float* out1 = out0 + NRES;                   // [N,2]

  hipMemsetAsync(agg, 0, (size_t)NRES * 128 * sizeof(float), stream);

  k_xa      <<<12500, 256, 0, stream>>>(z, bb, side, W_emb, b_emb, x);
  k_esm     <<<782,   256, 0, stream>>>(esm, W_esm, b_esm, x);
  k_nodehead<<<6250,  256, 0, stream>>>(x, W_n0, b_n0, W_nf, b_nf, out1);
  k_edge    <<<31250, 128, 0, stream>>>(ei, pos, posn, posc, x, W_edge, W_msg, agg);
  k_upd     <<<1563,  128, 0, stream>>>(x, agg, W_upd, W_o0, b_o0, W_o1, b_o1,
                                        W_of, b_of, out0);
}

// Round 2
// 1072.430 us; speedup vs baseline: 3.2573x; 3.2573x over previous
//
#include <hip/hip_runtime.h>
#include <math.h>

#define NRES 50000
#define NEDGE 1000000
#define PI_F 3.14159265358979323846f

typedef __attribute__((ext_vector_type(8))) short short8;
typedef __attribute__((ext_vector_type(4))) float floatx4;

struct f3 { float x, y, z; };
__device__ __forceinline__ f3 ld3(const float* __restrict__ p, int i) {
  return {p[3*i+0], p[3*i+1], p[3*i+2]};
}
__device__ __forceinline__ f3 f3sub(f3 a, f3 b){ return {a.x-b.x, a.y-b.y, a.z-b.z}; }
__device__ __forceinline__ f3 f3cross(f3 a, f3 b){
  return {a.y*b.z - a.z*b.y, a.z*b.x - a.x*b.z, a.x*b.y - a.y*b.x};
}
__device__ __forceinline__ float f3dot(f3 a, f3 b){ return a.x*b.x + a.y*b.y + a.z*b.z; }
__device__ __forceinline__ float f3norm(f3 a){ return sqrtf(f3dot(a,a)); }
__device__ __forceinline__ float sigmoidf(float v){ return 1.0f/(1.0f + expf(-v)); }
__device__ __forceinline__ float swishf(float v){ return v * sigmoidf(v); }
__device__ __forceinline__ short f2bf(float f){
  unsigned u = __float_as_uint(f);
  unsigned r = (u + 0x7fffu + ((u >> 16) & 1u)) >> 16;
  return (short)r;
}

// ---------------------------------------------------------------------------
// weight prep: convert W_edge/W_msg/W_esm to bf16 in MFMA B-fragment order.
// B-frag layout for 16x16x32: lane holds B[k=(lane>>4)*8+j][n=lane&15], j=0..7
// Wef: [4kt][8nt][64lane][8j]  (k>=124 zero-padded)
// Wmf: [4kt][8nt][64lane][8j]
// Wsf: [40kt][4nt][64lane][8j]
__global__ __launch_bounds__(256) void k_wprep(
    const float* __restrict__ We, const float* __restrict__ Wm,
    const float* __restrict__ Ws, short* __restrict__ Wef,
    short* __restrict__ Wmf, short* __restrict__ Wsf)
{
  int gid = blockIdx.x * 256 + threadIdx.x;   // 0..114687
  if (gid < 16384) {
    int t = gid;
    int j = t & 7, lane = (t >> 3) & 63, nt = (t >> 9) & 7, kt = t >> 12;
    int k = kt*32 + (lane >> 4)*8 + j, n = nt*16 + (lane & 15);
    float v = (k < 124) ? We[k*128 + n] : 0.0f;
    Wef[t] = f2bf(v);
  } else if (gid < 32768) {
    int t = gid - 16384;
    int j = t & 7, lane = (t >> 3) & 63, nt = (t >> 9) & 7, kt = t >> 12;
    int k = kt*32 + (lane >> 4)*8 + j, n = nt*16 + (lane & 15);
    Wmf[t] = f2bf(Wm[k*128 + n]);
  } else {
    int t = gid - 32768;                      // 0..81919
    int j = t & 7, lane = (t >> 3) & 63, nt = (t >> 9) & 3, kt = t >> 11;
    int k = kt*32 + (lane >> 4)*8 + j, n = nt*16 + (lane & 15);
    Wsf[t] = f2bf(Ws[k*64 + n]);
  }
}

// ---------------------------------------------------------------------------
// x_a: [oh(26)|bb(6)|side(8)] @ W_emb[40,64] + b_emb  -> x[:, 0:64]
__global__ __launch_bounds__(256) void k_xa(
    const int* __restrict__ z, const float* __restrict__ bb,
    const float* __restrict__ side, const float* __restrict__ W_emb,
    const float* __restrict__ b_emb, float* __restrict__ x)
{
  int tid = threadIdx.x;
  int h = tid & 63;
  int n = blockIdx.x * 4 + (tid >> 6);
  if (n >= NRES) return;
  int zz = z[n];
  float acc = W_emb[zz * 64 + h] + b_emb[h];
  #pragma unroll
  for (int k = 0; k < 6; ++k) acc += bb[n*6 + k] * W_emb[(26 + k)*64 + h];
  #pragma unroll
  for (int k = 0; k < 8; ++k) acc += side[n*8 + k] * W_emb[(32 + k)*64 + h];
  x[(size_t)n * 128 + h] = acc;
}

// ---------------------------------------------------------------------------
// x_s = esm[50000,1280] @ W_esm[1280,64] + b_esm  (bf16 MFMA, BK=128 chunks)
// 256 threads = 4 waves; wave w owns M-rows [w*16, w*16+16), N=64 (4 ntiles)
__global__ __launch_bounds__(256) void k_esm(
    const float* __restrict__ esm, const short* __restrict__ Wsf,
    const float* __restrict__ b, float* __restrict__ x)
{
  __shared__ __align__(16) short sA[64][136];   // bf16 esm tile, +8 pad
  const int tid = threadIdx.x;
  const int lane = tid & 63, w = tid >> 6;
  const int quad = lane >> 4, colb = lane & 15;
  const int n0 = blockIdx.x * 64;

  floatx4 acc[4];
  #pragma unroll
  for (int nt = 0; nt < 4; ++nt) acc[nt] = (floatx4){0.f, 0.f, 0.f, 0.f};

  for (int kc = 0; kc < 10; ++kc) {
    // stage 64 rows x 128 cols: 2048 float4 over 256 threads
    #pragma unroll
    for (int it = 0; it < 8; ++it) {
      int idx = it * 256 + tid;
      int row = idx >> 5, c4 = idx & 31;
      int n = n0 + row;
      float4 v = make_float4(0.f, 0.f, 0.f, 0.f);
      if (n < NRES) v = *(const float4*)&esm[(size_t)n * 1280 + kc*128 + c4*4];
      short* dst = &sA[row][c4*4];
      dst[0] = f2bf(v.x); dst[1] = f2bf(v.y);
      dst[2] = f2bf(v.z); dst[3] = f2bf(v.w);
    }
    __syncthreads();
    #pragma unroll
    for (int kt = 0; kt < 4; ++kt) {
      int gkt = kc*4 + kt;
      short8 a = *(const short8*)&sA[w*16 + colb][kt*32 + quad*8];
      #pragma unroll
      for (int nt = 0; nt < 4; ++nt) {
        short8 bf = *(const short8*)&Wsf[(size_t)((gkt*4 + nt)*64 + lane)*8];
        acc[nt] = __builtin_amdgcn_mfma_f32_16x16x32_bf16(a, bf, acc[nt], 0, 0, 0);
      }
    }
    __syncthreads();
  }
  #pragma unroll
  for (int nt = 0; nt < 4; ++nt) {
    int ch = nt*16 + colb;
    float bias = b[ch];
    #pragma unroll
    for (int r = 0; r < 4; ++r) {
      int n = n0 + w*16 + quad*4 + r;
      if (n < NRES) x[(size_t)n * 128 + 64 + ch] = acc[nt][r] + bias;
    }
  }
}

// ---------------------------------------------------------------------------
// node head: node_out = relu(x @ W_n0 + b_n0) @ W_nf + b_nf
__global__ __launch_bounds__(256) void k_nodehead(
    const float* __restrict__ x, const float* __restrict__ Wn0,
    const float* __restrict__ bn0, const float* __restrict__ Wnf,
    const float* __restrict__ bnf, float* __restrict__ out1)
{
  __shared__ float sXN[8][36];
  int tid = threadIdx.x;
  int nl = tid >> 5, ch = tid & 31;
  int n = blockIdx.x * 8 + nl;
  const float* xr = &x[(size_t)n * 128];
  float a = bn0[ch];
  for (int k = 0; k < 128; ++k) a += xr[k] * Wn0[k * 32 + ch];
  sXN[nl][ch] = fmaxf(a, 0.0f);
  __syncthreads();
  if (tid < 16) {
    int nl2 = tid >> 1, oc = tid & 1;
    int nn = blockIdx.x * 8 + nl2;
    float a2 = bnf[oc];
    #pragma unroll
    for (int k = 0; k < 32; ++k) a2 += sXN[nl2][k] * Wnf[k * 2 + oc];
    out1[(size_t)nn * 2 + oc] = a2;
  }
}

// ---------------------------------------------------------------------------
// edge kernel (MFMA): 64 edges/block, 256 threads = 4 waves.
// wave 0: geometry (1 edge/lane) -> sF bf16; waves 1-3: gather x[j] -> sXJ bf16.
// Then dual GEMM [64 x 128] K=128 via mfma 16x16x32 bf16; wave w owns cols
// [w*32, w*32+32). m = swish(xj@Wm)*swish(f@We); atomicAdd into agg[i].
__global__ __launch_bounds__(256, 3) void k_edge(
    const int* __restrict__ ei, const float* __restrict__ pos,
    const float* __restrict__ posn, const float* __restrict__ posc,
    const float* __restrict__ x, const short* __restrict__ Wef,
    const short* __restrict__ Wmf, float* __restrict__ agg)
{
  __shared__ int sJ[64];
  __shared__ int sI[64];
  __shared__ __align__(16) short sF[64][136];    // edge features bf16, +8 pad
  __shared__ __align__(16) short sXJ[64][136];   // gathered x[j] bf16

  const int tid = threadIdx.x;
  const int e0 = blockIdx.x * 64;

  if (tid < 64) { sJ[tid] = ei[e0 + tid]; sI[tid] = ei[NEDGE + e0 + tid]; }
  __syncthreads();

  if (tid < 64) {
    const int e = tid;
    const int j = sJ[e], i = sI[e];
    f3 pj = ld3(pos, j), pi = ld3(pos, i);
    f3 vji = f3sub(pj, pi);
    float dist = f3norm(vji);
    int r0i = (i == 0) ? (NRES - 1) : (i - 1);
    int r1i = (i == NRES - 1) ? 0 : (i + 1);
    f3 vr0 = f3sub(ld3(pos, r0i), pi);
    f3 vr1 = f3sub(ld3(pos, r1i), pi);
    float ta = f3dot(vji, vr0);
    float tb = f3norm(f3cross(vji, vr0));
    float theta = atan2f(tb, ta);
    f3 p1 = f3cross(vr0, vr1);
    f3 p2 = f3cross(vr0, vji);
    float pa = f3dot(p1, p2);
    float pb = f3dot(f3cross(p1, p2), vr0) / (f3norm(vr0) + 1e-7f);
    float phi = atan2f(pb, pa);

    f3 pni = ld3(posn, i), pci = ld3(posc, i);
    f3 o1x = f3sub(pni, pi);
    f3 o1z = f3cross(o1x, f3cross(o1x, f3sub(pci, pi)));
    float o1zl = f3norm(o1z) + 1e-7f;
    f3 pnj = ld3(posn, j), pcj = ld3(posc, j);
    f3 o2x = f3sub(pnj, pj);
    f3 o2z = f3cross(o2x, f3cross(o2x, f3sub(pcj, pj)));
    float o2zl = f3norm(o2z) + 1e-7f;
    f3 nv = f3cross(o1z, o2z);
    float an1 = atan2f(f3dot(f3cross(o1x, nv), o1z) / o1zl, f3dot(o1x, nv));
    float an2 = atan2f(f3norm(nv), f3dot(o1z, o2z));
    float an3 = atan2f(f3dot(f3cross(nv, o2x), o2z) / o2zl, f3dot(nv, o2x));

    float u = fminf(dist / 11.5f, 1.0f);
    float fc = 0.5f * (cosf(PI_F * u) + 1.0f);
    float pref = 0.41702882811414954f / (dist + 1e-6f) * fc;  // sqrt(2/11.5)
    float rb[6];
    #pragma unroll
    for (int nn = 0; nn < 6; ++nn) rb[nn] = pref * sinf((float)(nn + 1) * PI_F * u);

    float ctv[3] = {1.0f, cosf(theta), cosf(2.0f * theta)};
    float cpv[3] = {1.0f, cosf(phi),   cosf(2.0f * phi)};
    #pragma unroll
    for (int nn = 0; nn < 6; ++nn)
      #pragma unroll
      for (int l = 0; l < 3; ++l)
        #pragma unroll
        for (int m = 0; m < 3; ++m)
          sF[e][nn*9 + l*3 + m] = f2bf(rb[nn] * ctv[l] * cpv[m]);

    float angs[3] = {an1, an2, an3};
    #pragma unroll
    for (int t = 0; t < 3; ++t) {
      float cav[3] = {1.0f, cosf(angs[t]), cosf(2.0f * angs[t])};
      #pragma unroll
      for (int nn = 0; nn < 6; ++nn)
        #pragma unroll
        for (int l = 0; l < 3; ++l)
          sF[e][54 + t*18 + nn*3 + l] = f2bf(rb[nn] * cav[l]);
    }

    const float FRQ[8] = {1.0f, 0.31622776601683794f, 0.1f, 0.03162277660168379f,
                          0.01f, 0.003162277660168379f, 0.001f, 0.0003162277660168379f};
    float dpe = (float)(j - i);
    #pragma unroll
    for (int q = 0; q < 8; ++q) {
      float s, c;
      sincosf(dpe * FRQ[q], &s, &c);
      sF[e][108 + q] = f2bf(c);
      sF[e][116 + q] = f2bf(s);
    }
    sF[e][124] = 0; sF[e][125] = 0; sF[e][126] = 0; sF[e][127] = 0;
  } else {
    // threads 64..255 gather x[j] (f32) -> sXJ (bf16): 2048 float4 total
    const int t2 = tid - 64;
    for (int it = 0; it < 11; ++it) {
      int idx = it * 192 + t2;
      if (idx < 2048) {
        int row = idx >> 5;
        int c4 = idx & 31;
        float4 v = *(const float4*)&x[(size_t)sJ[row] * 128 + c4*4];
        short* dst = &sXJ[row][c4*4];
        dst[0] = f2bf(v.x); dst[1] = f2bf(v.y);
        dst[2] = f2bf(v.z); dst[3] = f2bf(v.w);
      }
    }
  }
  __syncthreads();

  const int lane = tid & 63, w = tid >> 6;
  const int quad = lane >> 4, colb = lane & 15;
  const int nb = w * 2;   // ntile base: wave w covers ntiles nb, nb+1

  // B fragments from frag-ordered global (L2-resident)
  short8 bE[4][2], bM[4][2];
  #pragma unroll
  for (int kt = 0; kt < 4; ++kt)
    #pragma unroll
    for (int nt = 0; nt < 2; ++nt) {
      bE[kt][nt] = *(const short8*)&Wef[(size_t)((kt*8 + nb + nt)*64 + lane)*8];
      bM[kt][nt] = *(const short8*)&Wmf[(size_t)((kt*8 + nb + nt)*64 + lane)*8];
    }

  floatx4 accE[4][2], accM[4][2];
  #pragma unroll
  for (int mt = 0; mt < 4; ++mt)
    #pragma unroll
    for (int nt = 0; nt < 2; ++nt) {
      accE[mt][nt] = (floatx4){0.f, 0.f, 0.f, 0.f};
      accM[mt][nt] = (floatx4){0.f, 0.f, 0.f, 0.f};
    }

  #pragma unroll
  for (int kt = 0; kt < 4; ++kt) {
    #pragma unroll
    for (int mt = 0; mt < 4; ++mt) {
      short8 af = *(const short8*)&sF [mt*16 + colb][kt*32 + quad*8];
      short8 ax = *(const short8*)&sXJ[mt*16 + colb][kt*32 + quad*8];
      #pragma unroll
      for (int nt = 0; nt < 2; ++nt) {
        accE[mt][nt] = __builtin_amdgcn_mfma_f32_16x16x32_bf16(af, bE[kt][nt], accE[mt][nt], 0, 0, 0);
        accM[mt][nt] = __builtin_amdgcn_mfma_f32_16x16x32_bf16(ax, bM[kt][nt], accM[mt][nt], 0, 0, 0);
      }
    }
  }

  // epilogue: m = swish(m)*swish(ef), scatter-add to agg[i]
  #pragma unroll
  for (int mt = 0; mt < 4; ++mt) {
    #pragma unroll
    for (int r = 0; r < 4; ++r) {
      int e = mt*16 + quad*4 + r;
      int idst = sI[e];
      float* arow = agg + (size_t)idst * 128;
      #pragma unroll
      for (int nt = 0; nt < 2; ++nt) {
        int ch = w*32 + nt*16 + colb;
        float mval = swishf(accM[mt][nt][r]) * swishf(accE[mt][nt][r]);
        atomicAdd(arow + ch, mval);
      }
    }
  }
}

// ---------------------------------------------------------------------------
// update + out head: xe = x + swish(agg@W_upd); h = relu(xe@W_o0+b);
// h2 = relu(h@W_o1+b); out = sigmoid(h2@W_of+b). 32 nodes / 128-thread block.
__global__ __launch_bounds__(128) void k_upd(
    const float* __restrict__ x, const float* __restrict__ agg,
    const float* __restrict__ Wu, const float* __restrict__ Wo0,
    const float* __restrict__ bo0, const float* __restrict__ Wo1,
    const float* __restrict__ bo1, const float* __restrict__ Wof,
    const float* __restrict__ bof, float* __restrict__ out)
{
  __shared__ __align__(16) float sIn[32][132];
  __shared__ __align__(16) float sXE[32][132];
  __shared__ __align__(16) float sH[32][132];
  __shared__ __align__(16) float sW[16][128];
  __shared__ __align__(16) float sH2[32][36];

  const int tid = threadIdx.x;
  const int tx = tid & 15, ty = tid >> 4;
  const int n0 = blockIdx.x * 32;

  #pragma unroll
  for (int it = 0; it < 8; ++it) {
    int idx = it * 128 + tid;
    int row = idx >> 5, c = (idx & 31) << 2;
    int n = n0 + row;
    float4 v = make_float4(0.f, 0.f, 0.f, 0.f);
    if (n < NRES) v = *(const float4*)&agg[(size_t)n * 128 + c];
    *(float4*)&sIn[row][c] = v;
  }
  __syncthreads();

  float acc[4][8];
  #pragma unroll
  for (int u = 0; u < 4; ++u)
    #pragma unroll
    for (int v = 0; v < 8; ++v) acc[u][v] = 0.0f;

  for (int kt = 0; kt < 8; ++kt) {
    #pragma unroll
    for (int it = 0; it < 4; ++it) {
      int idx = it * 128 + tid;
      int k = idx >> 5, c = (idx & 31) << 2;
      *(float4*)&sW[k][c] = *(const float4*)&Wu[(size_t)(kt*16 + k) * 128 + c];
    }
    __syncthreads();
    #pragma unroll
    for (int kk = 0; kk < 16; ++kk) {
      int gk = kt * 16 + kk;
      float a[4];
      #pragma unroll
      for (int u = 0; u < 4; ++u) a[u] = sIn[4*ty + u][gk];
      float4 w0 = *(const float4*)&sW[kk][4*tx];
      float4 w1 = *(const float4*)&sW[kk][64 + 4*tx];
      #pragma unroll
      for (int u = 0; u < 4; ++u) {
        acc[u][0] += a[u]*w0.x; acc[u][1] += a[u]*w0.y;
        acc[u][2] += a[u]*w0.z; acc[u][3] += a[u]*w0.w;
        acc[u][4] += a[u]*w1.x; acc[u][5] += a[u]*w1.y;
        acc[u][6] += a[u]*w1.z; acc[u][7] += a[u]*w1.w;
      }
    }
    __syncthreads();
  }
  #pragma unroll
  for (int u = 0; u < 4; ++u) {
    int row = 4*ty + u;
    int n = n0 + row;
    #pragma unroll
    for (int cb = 0; cb < 2; ++cb) {
      int ch = cb*64 + 4*tx;
      float4 xv = make_float4(0.f, 0.f, 0.f, 0.f);
      if (n < NRES) xv = *(const float4*)&x[(size_t)n * 128 + ch];
      float4 o;
      o.x = xv.x + swishf(acc[u][cb*4 + 0]);
      o.y = xv.y + swishf(acc[u][cb*4 + 1]);
      o.z = xv.z + swishf(acc[u][cb*4 + 2]);
      o.w = xv.w + swishf(acc[u][cb*4 + 3]);
      *(float4*)&sXE[row][ch] = o;
    }
  }
  __syncthreads();

  float acc2[4][8];
  #pragma unroll
  for (int u = 0; u < 4; ++u)
    #pragma unroll
    for (int v = 0; v < 8; ++v) acc2[u][v] = 0.0f;

  for (int kt = 0; kt < 8; ++kt) {
    #pragma unroll
    for (int it = 0; it < 4; ++it) {
      int idx = it * 128 + tid;
      int k = idx >> 5, c = (idx & 31) << 2;
      *(float4*)&sW[k][c] = *(const float4*)&Wo0[(size_t)(kt*16 + k) * 128 + c];
    }
    __syncthreads();
    #pragma unroll
    for (int kk = 0; kk < 16; ++kk) {
      int gk = kt * 16 + kk;
      float a[4];
      #pragma unroll
      for (int u = 0; u < 4; ++u) a[u] = sXE[4*ty + u][gk];
      float4 w0 = *(const float4*)&sW[kk][4*tx];
      float4 w1 = *(const float4*)&sW[kk][64 + 4*tx];
      #pragma unroll
      for (int u = 0; u < 4; ++u) {
        acc2[u][0] += a[u]*w0.x; acc2[u][1] += a[u]*w0.y;
        acc2[u][2] += a[u]*w0.z; acc2[u][3] += a[u]*w0.w;
        acc2[u][4] += a[u]*w1.x; acc2[u][5] += a[u]*w1.y;
        acc2[u][6] += a[u]*w1.z; acc2[u][7] += a[u]*w1.w;
      }
    }
    __syncthreads();
  }
  {
    float4 b0 = *(const float4*)&bo0[4*tx];
    float4 b1 = *(const float4*)&bo0[64 + 4*tx];
    float bb0[4] = {b0.x, b0.y, b0.z, b0.w};
    float bb1[4] = {b1.x, b1.y, b1.z, b1.w};
    #pragma unroll
    for (int u = 0; u < 4; ++u) {
      int row = 4*ty + u;
      #pragma unroll
      for (int v = 0; v < 4; ++v) {
        sH[row][4*tx + v]      = fmaxf(acc2[u][v]     + bb0[v], 0.0f);
        sH[row][64 + 4*tx + v] = fmaxf(acc2[u][4 + v] + bb1[v], 0.0f);
      }
    }
  }
  __syncthreads();

  {
    int ch = tid & 31, rp = tid >> 5;
    #pragma unroll
    for (int p = 0; p < 8; ++p) {
      int row = p * 4 + rp;
      float a = bo1[ch];
      for (int k = 0; k < 128; ++k) a += sH[row][k] * Wo1[k * 32 + ch];
      sH2[row][ch] = fmaxf(a, 0.0f);
    }
  }
  __syncthreads();

  if (tid < 32) {
    int n = n0 + tid;
    if (n < NRES) {
      float a = bof[0];
      #pragma unroll
      for (int k = 0; k < 32; ++k) a += sH2[tid][k] * Wof[k];
      out[n] = sigmoidf(a);
    }
  }
}

// ---------------------------------------------------------------------------
extern "C" void kernel_launch(void* const* d_in, const int* in_sizes, int n_in,
                              void* d_out, int out_size, void* d_ws, size_t ws_size,
                              hipStream_t stream) {
  (void)in_sizes; (void)n_in; (void)out_size; (void)ws_size;
  const int*   z     = (const int*)  d_in[0];
  const float* pos   = (const float*)d_in[1];
  const float* posn  = (const float*)d_in[2];
  const float* posc  = (const float*)d_in[3];
  const float* bb    = (const float*)d_in[4];
  const float* side  = (const float*)d_in[5];
  const float* esm   = (const float*)d_in[6];
  const int*   ei    = (const int*)  d_in[8];
  const float* W_emb = (const float*)d_in[9];
  const float* b_emb = (const float*)d_in[10];
  const float* W_esm = (const float*)d_in[11];
  const float* b_esm = (const float*)d_in[12];
  const float* W_edge= (const float*)d_in[13];
  const float* W_msg = (const float*)d_in[14];
  const float* W_upd = (const float*)d_in[15];
  const float* W_o0  = (const float*)d_in[16];
  const float* b_o0  = (const float*)d_in[17];
  const float* W_o1  = (const float*)d_in[18];
  const float* b_o1  = (const float*)d_in[19];
  const float* W_of  = (const float*)d_in[20];
  const float* b_of  = (const float*)d_in[21];
  const float* W_n0  = (const float*)d_in[22];
  const float* b_n0  = (const float*)d_in[23];
  const float* W_nf  = (const float*)d_in[24];
  const float* b_nf  = (const float*)d_in[25];

  char* ws = (char*)d_ws;
  float* x    = (float*)ws;                            // 25,600,000 B
  float* agg  = (float*)(ws + 25600000);               // 25,600,000 B
  short* Wef  = (short*)(ws + 51200000);               // 32,768 B
  short* Wmf  = (short*)(ws + 51232768);               // 32,768 B
  short* Wsf  = (short*)(ws + 51265536);               // 163,840 B
  float* out0 = (float*)d_out;                         // [N]
  float* out1 = out0 + NRES;                           // [N,2]

  hipMemsetAsync(agg, 0, (size_t)NRES * 128 * sizeof(float), stream);

  k_wprep   <<<448,   256, 0, stream>>>(W_edge, W_msg, W_esm, Wef, Wmf, Wsf);
  k_xa      <<<12500, 256, 0, stream>>>(z, bb, side, W_emb, b_emb, x);
  k_esm     <<<782,   256, 0, stream>>>(esm, Wsf, b_esm, x);
  k_nodehead<<<6250,  256, 0, stream>>>(x, W_n0, b_n0, W_nf, b_nf, out1);
  k_edge    <<<15625, 256, 0, stream>>>(ei, pos, posn, posc, x, Wef, Wmf, agg);
  k_upd     <<<1563,  128, 0, stream>>>(x, agg, W_upd, W_o0, b_o0, W_o1, b_o1,
                                        W_of, b_of, out0);
}

// Round 3
// 884.175 us; speedup vs baseline: 3.9508x; 1.2129x over previous
//
#include <hip/hip_runtime.h>
#include <math.h>

#define NRES 50000
#define NEDGE 1000000
#define PI_F 3.14159265358979323846f

typedef __attribute__((ext_vector_type(8))) short short8;
typedef __attribute__((ext_vector_type(4))) float floatx4;

struct f3 { float x, y, z; };
__device__ __forceinline__ f3 ld3(const float* __restrict__ p, int i) {
  return {p[3*i+0], p[3*i+1], p[3*i+2]};
}
__device__ __forceinline__ f3 f3sub(f3 a, f3 b){ return {a.x-b.x, a.y-b.y, a.z-b.z}; }
__device__ __forceinline__ f3 f3cross(f3 a, f3 b){
  return {a.y*b.z - a.z*b.y, a.z*b.x - a.x*b.z, a.x*b.y - a.y*b.x};
}
__device__ __forceinline__ float f3dot(f3 a, f3 b){ return a.x*b.x + a.y*b.y + a.z*b.z; }
__device__ __forceinline__ float f3norm(f3 a){ return sqrtf(f3dot(a,a)); }
__device__ __forceinline__ float swish_fast(float v){
  return v * __builtin_amdgcn_rcpf(1.0f + __expf(-v));
}
__device__ __forceinline__ short f2bf(float f){
  unsigned u = __float_as_uint(f);
  unsigned r = (u + 0x7fffu + ((u >> 16) & 1u)) >> 16;
  return (short)r;
}
// cos(atan2(y,x)) robustly: x * rsqrt(x^2+y^2)
__device__ __forceinline__ float cos_atan2(float y, float x){
  return x * __builtin_amdgcn_rsqf(fmaxf(x*x + y*y, 1e-30f));
}

// ---------------------------------------------------------------------------
// weight prep -> bf16 MFMA B-fragment order.
// frag layout: t = ((kt*NT + nt)*64 + lane)*8 + j ; k = kt*32+(lane>>4)*8+j ;
//              n = nt*16+(lane&15) ; zero-pad k >= K.
__global__ __launch_bounds__(256) void k_wprep(
    const float* __restrict__ We, const float* __restrict__ Wm,
    const float* __restrict__ Ws, const float* __restrict__ Wu,
    const float* __restrict__ Wo0, const float* __restrict__ Wn0,
    const float* __restrict__ Wo1,
    short* __restrict__ Wef, short* __restrict__ Wmf, short* __restrict__ Wsf,
    short* __restrict__ Wuf, short* __restrict__ Wo0f,
    short* __restrict__ Wn0f, short* __restrict__ Wo1f)
{
  int gid = blockIdx.x * 256 + threadIdx.x;
  const float* src; short* dst; int NT, K, N, t;
  if      (gid < 16384)  { t = gid;          src = We;  dst = Wef;  NT = 8; K = 124;  N = 128; }
  else if (gid < 32768)  { t = gid - 16384;  src = Wm;  dst = Wmf;  NT = 8; K = 128;  N = 128; }
  else if (gid < 114688) { t = gid - 32768;  src = Ws;  dst = Wsf;  NT = 4; K = 1280; N = 64;  }
  else if (gid < 131072) { t = gid - 114688; src = Wu;  dst = Wuf;  NT = 8; K = 128;  N = 128; }
  else if (gid < 147456) { t = gid - 131072; src = Wo0; dst = Wo0f; NT = 8; K = 128;  N = 128; }
  else if (gid < 151552) { t = gid - 147456; src = Wn0; dst = Wn0f; NT = 2; K = 128;  N = 32;  }
  else if (gid < 155648) { t = gid - 151552; src = Wo1; dst = Wo1f; NT = 2; K = 128;  N = 32;  }
  else return;
  int j = t & 7, lane = (t >> 3) & 63;
  int rest = t >> 9;
  int nt = rest % NT, kt = rest / NT;
  int k = kt*32 + (lane >> 4)*8 + j, n = nt*16 + (lane & 15);
  dst[t] = f2bf((k < K) ? src[k*N + n] : 0.0f);
}

// ---------------------------------------------------------------------------
// x_a: [oh(26)|bb(6)|side(8)] @ W_emb[40,64] + b_emb  -> x[:, 0:64]
__global__ __launch_bounds__(256) void k_xa(
    const int* __restrict__ z, const float* __restrict__ bb,
    const float* __restrict__ side, const float* __restrict__ W_emb,
    const float* __restrict__ b_emb, float* __restrict__ x)
{
  int tid = threadIdx.x;
  int h = tid & 63;
  int n = blockIdx.x * 4 + (tid >> 6);
  if (n >= NRES) return;
  int zz = z[n];
  float acc = W_emb[zz * 64 + h] + b_emb[h];
  #pragma unroll
  for (int k = 0; k < 6; ++k) acc += bb[n*6 + k] * W_emb[(26 + k)*64 + h];
  #pragma unroll
  for (int k = 0; k < 8; ++k) acc += side[n*8 + k] * W_emb[(32 + k)*64 + h];
  x[(size_t)n * 128 + h] = acc;
}

// ---------------------------------------------------------------------------
// x_s = esm[50000,1280] @ W_esm[1280,64] + b_esm  (bf16 MFMA, BK=128 chunks)
__global__ __launch_bounds__(256) void k_esm(
    const float* __restrict__ esm, const short* __restrict__ Wsf,
    const float* __restrict__ b, float* __restrict__ x)
{
  __shared__ __align__(16) short sA[64][136];
  const int tid = threadIdx.x;
  const int lane = tid & 63, w = tid >> 6;
  const int quad = lane >> 4, colb = lane & 15;
  const int n0 = blockIdx.x * 64;

  floatx4 acc[4];
  #pragma unroll
  for (int nt = 0; nt < 4; ++nt) acc[nt] = (floatx4){0.f, 0.f, 0.f, 0.f};

  for (int kc = 0; kc < 10; ++kc) {
    #pragma unroll
    for (int it = 0; it < 8; ++it) {
      int idx = it * 256 + tid;
      int row = idx >> 5, c4 = idx & 31;
      int n = n0 + row;
      float4 v = make_float4(0.f, 0.f, 0.f, 0.f);
      if (n < NRES) v = *(const float4*)&esm[(size_t)n * 1280 + kc*128 + c4*4];
      short* dst = &sA[row][c4*4];
      dst[0] = f2bf(v.x); dst[1] = f2bf(v.y);
      dst[2] = f2bf(v.z); dst[3] = f2bf(v.w);
    }
    __syncthreads();
    #pragma unroll
    for (int kt = 0; kt < 4; ++kt) {
      int gkt = kc*4 + kt;
      short8 a = *(const short8*)&sA[w*16 + colb][kt*32 + quad*8];
      #pragma unroll
      for (int nt = 0; nt < 4; ++nt) {
        short8 bf = *(const short8*)&Wsf[(size_t)((gkt*4 + nt)*64 + lane)*8];
        acc[nt] = __builtin_amdgcn_mfma_f32_16x16x32_bf16(a, bf, acc[nt], 0, 0, 0);
      }
    }
    __syncthreads();
  }
  #pragma unroll
  for (int nt = 0; nt < 4; ++nt) {
    int ch = nt*16 + colb;
    float bias = b[ch];
    #pragma unroll
    for (int r = 0; r < 4; ++r) {
      int n = n0 + w*16 + quad*4 + r;
      if (n < NRES) x[(size_t)n * 128 + 64 + ch] = acc[nt][r] + bias;
    }
  }
}

// ---------------------------------------------------------------------------
// edge kernel (MFMA): 64 edges/block, 256 threads = 4 waves.
__global__ __launch_bounds__(256, 3) void k_edge(
    const int* __restrict__ ei, const float* __restrict__ pos,
    const float* __restrict__ posn, const float* __restrict__ posc,
    const float* __restrict__ x, const short* __restrict__ Wef,
    const short* __restrict__ Wmf, float* __restrict__ agg)
{
  __shared__ int sJ[64];
  __shared__ int sI[64];
  __shared__ __align__(16) short sF[64][136];
  __shared__ __align__(16) short sXJ[64][136];

  const int tid = threadIdx.x;
  const int e0 = blockIdx.x * 64;

  if (tid < 64) { sJ[tid] = ei[e0 + tid]; sI[tid] = ei[NEDGE + e0 + tid]; }
  __syncthreads();

  if (tid < 64) {
    const int e = tid;
    const int j = sJ[e], i = sI[e];
    f3 pj = ld3(pos, j), pi = ld3(pos, i);
    f3 vji = f3sub(pj, pi);
    float nji2 = f3dot(vji, vji);
    float dist = sqrtf(nji2);
    int r0i = (i == 0) ? (NRES - 1) : (i - 1);
    int r1i = (i == NRES - 1) ? 0 : (i + 1);
    f3 vr0 = f3sub(ld3(pos, r0i), pi);
    f3 vr1 = f3sub(ld3(pos, r1i), pi);
    float nr02 = f3dot(vr0, vr0);

    // cos(theta), theta = atan2(|vji x vr0|, vji.vr0); x^2+y^2 = |vji|^2|vr0|^2
    float ct = f3dot(vji, vr0) * __builtin_amdgcn_rsqf(fmaxf(nji2 * nr02, 1e-30f));
    // cos(phi)
    f3 p1 = f3cross(vr0, vr1);
    f3 p2 = f3cross(vr0, vji);
    float pa = f3dot(p1, p2);
    float pb = f3dot(f3cross(p1, p2), vr0) / (sqrtf(nr02) + 1e-7f);
    float cp = cos_atan2(pb, pa);

    // backbone frames
    f3 pni = ld3(posn, i), pci = ld3(posc, i);
    f3 o1x = f3sub(pni, pi);
    f3 o1z = f3cross(o1x, f3cross(o1x, f3sub(pci, pi)));
    float no1z2 = f3dot(o1z, o1z);
    float o1zl = sqrtf(no1z2) + 1e-7f;
    f3 pnj = ld3(posn, j), pcj = ld3(posc, j);
    f3 o2x = f3sub(pnj, pj);
    f3 o2z = f3cross(o2x, f3cross(o2x, f3sub(pcj, pj)));
    float no2z2 = f3dot(o2z, o2z);
    float o2zl = sqrtf(no2z2) + 1e-7f;
    f3 nv = f3cross(o1z, o2z);
    // cos(angle1) = cos(atan2(y1,x1))
    float y1 = f3dot(f3cross(o1x, nv), o1z) / o1zl;
    float ca1 = cos_atan2(y1, f3dot(o1x, nv));
    // cos(angle2): y2=|nv|, x2=o1z.o2z ; x2^2+y2^2 = |o1z|^2|o2z|^2
    float ca2 = f3dot(o1z, o2z) * __builtin_amdgcn_rsqf(fmaxf(no1z2 * no2z2, 1e-30f));
    // cos(angle3)
    float y3 = f3dot(f3cross(nv, o2x), o2z) / o2zl;
    float ca3 = cos_atan2(y3, f3dot(nv, o2x));

    // radial basis: sin(n*pi*u) via Chebyshev recurrence
    float u = fminf(dist * (1.0f/11.5f), 1.0f);
    float spu, cpu;
    sincosf(PI_F * u, &spu, &cpu);
    float fc = 0.5f * (cpu + 1.0f);
    float pref = 0.41702882811414954f * __builtin_amdgcn_rcpf(dist + 1e-6f) * fc;
    float rb[6];
    {
      float twoc = 2.0f * cpu;
      float s_nm1 = 0.0f, s_n = spu;
      #pragma unroll
      for (int nn = 0; nn < 6; ++nn) {
        rb[nn] = pref * s_n;
        float s_np1 = twoc * s_n - s_nm1;
        s_nm1 = s_n; s_n = s_np1;
      }
    }

    float ctv[3] = {1.0f, ct, 2.0f*ct*ct - 1.0f};
    float cpv[3] = {1.0f, cp, 2.0f*cp*cp - 1.0f};
    #pragma unroll
    for (int nn = 0; nn < 6; ++nn)
      #pragma unroll
      for (int l = 0; l < 3; ++l)
        #pragma unroll
        for (int m = 0; m < 3; ++m)
          sF[e][nn*9 + l*3 + m] = f2bf(rb[nn] * ctv[l] * cpv[m]);

    float cas[3] = {ca1, ca2, ca3};
    #pragma unroll
    for (int t = 0; t < 3; ++t) {
      float c = cas[t];
      float cav[3] = {1.0f, c, 2.0f*c*c - 1.0f};
      #pragma unroll
      for (int nn = 0; nn < 6; ++nn)
        #pragma unroll
        for (int l = 0; l < 3; ++l)
          sF[e][54 + t*18 + nn*3 + l] = f2bf(rb[nn] * cav[l]);
    }

    const float FRQ[8] = {1.0f, 0.31622776601683794f, 0.1f, 0.03162277660168379f,
                          0.01f, 0.003162277660168379f, 0.001f, 0.0003162277660168379f};
    float dpe = (float)(j - i);
    #pragma unroll
    for (int q = 0; q < 8; ++q) {
      float s, c;
      sincosf(dpe * FRQ[q], &s, &c);   // accurate range reduction (large args)
      sF[e][108 + q] = f2bf(c);
      sF[e][116 + q] = f2bf(s);
    }
    sF[e][124] = 0; sF[e][125] = 0; sF[e][126] = 0; sF[e][127] = 0;
  } else {
    const int t2 = tid - 64;
    for (int it = 0; it < 11; ++it) {
      int idx = it * 192 + t2;
      if (idx < 2048) {
        int row = idx >> 5;
        int c4 = idx & 31;
        float4 v = *(const float4*)&x[(size_t)sJ[row] * 128 + c4*4];
        short* dst = &sXJ[row][c4*4];
        dst[0] = f2bf(v.x); dst[1] = f2bf(v.y);
        dst[2] = f2bf(v.z); dst[3] = f2bf(v.w);
      }
    }
  }
  __syncthreads();

  const int lane = tid & 63, w = tid >> 6;
  const int quad = lane >> 4, colb = lane & 15;
  const int nb = w * 2;

  short8 bE[4][2], bM[4][2];
  #pragma unroll
  for (int kt = 0; kt < 4; ++kt)
    #pragma unroll
    for (int nt = 0; nt < 2; ++nt) {
      bE[kt][nt] = *(const short8*)&Wef[(size_t)((kt*8 + nb + nt)*64 + lane)*8];
      bM[kt][nt] = *(const short8*)&Wmf[(size_t)((kt*8 + nb + nt)*64 + lane)*8];
    }

  floatx4 accE[4][2], accM[4][2];
  #pragma unroll
  for (int mt = 0; mt < 4; ++mt)
    #pragma unroll
    for (int nt = 0; nt < 2; ++nt) {
      accE[mt][nt] = (floatx4){0.f, 0.f, 0.f, 0.f};
      accM[mt][nt] = (floatx4){0.f, 0.f, 0.f, 0.f};
    }

  #pragma unroll
  for (int kt = 0; kt < 4; ++kt) {
    #pragma unroll
    for (int mt = 0; mt < 4; ++mt) {
      short8 af = *(const short8*)&sF [mt*16 + colb][kt*32 + quad*8];
      short8 ax = *(const short8*)&sXJ[mt*16 + colb][kt*32 + quad*8];
      #pragma unroll
      for (int nt = 0; nt < 2; ++nt) {
        accE[mt][nt] = __builtin_amdgcn_mfma_f32_16x16x32_bf16(af, bE[kt][nt], accE[mt][nt], 0, 0, 0);
        accM[mt][nt] = __builtin_amdgcn_mfma_f32_16x16x32_bf16(ax, bM[kt][nt], accM[mt][nt], 0, 0, 0);
      }
    }
  }

  #pragma unroll
  for (int mt = 0; mt < 4; ++mt) {
    #pragma unroll
    for (int r = 0; r < 4; ++r) {
      int e = mt*16 + quad*4 + r;
      int idst = sI[e];
      float* arow = agg + (size_t)idst * 128;
      #pragma unroll
      for (int nt = 0; nt < 2; ++nt) {
        int ch = w*32 + nt*16 + colb;
        float mval = swish_fast(accM[mt][nt][r]) * swish_fast(accE[mt][nt][r]);
        atomicAdd(arow + ch, mval);
      }
    }
  }
}

// ---------------------------------------------------------------------------
// fused update + both heads (MFMA). 64 nodes/block, 256 threads = 4 waves.
// hn = relu(x@Wn0+bn0); out1 = hn@Wnf+bnf
// xe = x + swish(agg@Wu); h = relu(xe@Wo0+bo0); h2 = relu(h@Wo1+bo1);
// out0 = sigmoid(h2@Wof+bof)
__global__ __launch_bounds__(256) void k_upd(
    const float* __restrict__ x, const float* __restrict__ agg,
    const short* __restrict__ Wuf, const short* __restrict__ Wo0f,
    const short* __restrict__ Wn0f, const short* __restrict__ Wo1f,
    const float* __restrict__ bn0, const float* __restrict__ Wnf,
    const float* __restrict__ bnf, const float* __restrict__ bo0,
    const float* __restrict__ bo1, const float* __restrict__ Wof,
    const float* __restrict__ bof, float* __restrict__ out0,
    float* __restrict__ out1)
{
  __shared__ __align__(16) short sA[64][136];   // agg bf16 -> xe bf16
  __shared__ __align__(16) short sX[64][136];   // x bf16   -> h  bf16
  __shared__ float sS[64][33];                  // hn / h2 scratch (f32)

  const int tid = threadIdx.x;
  const int lane = tid & 63, w = tid >> 6;
  const int quad = lane >> 4, colb = lane & 15;
  const int n0 = blockIdx.x * 64;

  #pragma unroll
  for (int it = 0; it < 8; ++it) {
    int idx = it * 256 + tid;
    int row = idx >> 5, c4 = idx & 31;
    int n = n0 + row;
    float4 va = make_float4(0.f, 0.f, 0.f, 0.f);
    float4 vx = make_float4(0.f, 0.f, 0.f, 0.f);
    if (n < NRES) {
      va = *(const float4*)&agg[(size_t)n * 128 + c4*4];
      vx = *(const float4*)&x  [(size_t)n * 128 + c4*4];
    }
    short* da = &sA[row][c4*4];
    da[0] = f2bf(va.x); da[1] = f2bf(va.y); da[2] = f2bf(va.z); da[3] = f2bf(va.w);
    short* dx = &sX[row][c4*4];
    dx[0] = f2bf(vx.x); dx[1] = f2bf(vx.y); dx[2] = f2bf(vx.z); dx[3] = f2bf(vx.w);
  }
  __syncthreads();

  // GEMM_n: wave w handles mtile w  (hn = relu(x@Wn0+bn0))
  {
    floatx4 accN[2];
    accN[0] = (floatx4){0.f,0.f,0.f,0.f}; accN[1] = (floatx4){0.f,0.f,0.f,0.f};
    #pragma unroll
    for (int kt = 0; kt < 4; ++kt) {
      short8 a = *(const short8*)&sX[w*16 + colb][kt*32 + quad*8];
      #pragma unroll
      for (int nt = 0; nt < 2; ++nt) {
        short8 bf = *(const short8*)&Wn0f[(size_t)((kt*2 + nt)*64 + lane)*8];
        accN[nt] = __builtin_amdgcn_mfma_f32_16x16x32_bf16(a, bf, accN[nt], 0, 0, 0);
      }
    }
    #pragma unroll
    for (int nt = 0; nt < 2; ++nt) {
      int col = nt*16 + colb;
      float bias = bn0[col];
      #pragma unroll
      for (int r = 0; r < 4; ++r)
        sS[w*16 + quad*4 + r][col] = fmaxf(accN[nt][r] + bias, 0.0f);
    }
  }
  __syncthreads();
  if (tid < 128) {
    int row = tid >> 1, oc = tid & 1;
    int n = n0 + row;
    if (n < NRES) {
      float a2 = bnf[oc];
      #pragma unroll
      for (int k = 0; k < 32; ++k) a2 += sS[row][k] * Wnf[k*2 + oc];
      out1[(size_t)n * 2 + oc] = a2;
    }
  }

  // GEMM1: t = agg@Wu ; wave w owns ntiles {2w,2w+1}
  floatx4 acc1[4][2];
  #pragma unroll
  for (int mt = 0; mt < 4; ++mt) {
    acc1[mt][0] = (floatx4){0.f,0.f,0.f,0.f};
    acc1[mt][1] = (floatx4){0.f,0.f,0.f,0.f};
  }
  #pragma unroll
  for (int kt = 0; kt < 4; ++kt) {
    short8 b0 = *(const short8*)&Wuf[(size_t)((kt*8 + w*2 + 0)*64 + lane)*8];
    short8 b1 = *(const short8*)&Wuf[(size_t)((kt*8 + w*2 + 1)*64 + lane)*8];
    #pragma unroll
    for (int mt = 0; mt < 4; ++mt) {
      short8 a = *(const short8*)&sA[mt*16 + colb][kt*32 + quad*8];
      acc1[mt][0] = __builtin_amdgcn_mfma_f32_16x16x32_bf16(a, b0, acc1[mt][0], 0, 0, 0);
      acc1[mt][1] = __builtin_amdgcn_mfma_f32_16x16x32_bf16(a, b1, acc1[mt][1], 0, 0, 0);
    }
  }
  __syncthreads();   // all reads of sA done; safe to overwrite with xe
  #pragma unroll
  for (int mt = 0; mt < 4; ++mt)
    #pragma unroll
    for (int nt = 0; nt < 2; ++nt)
      #pragma unroll
      for (int r = 0; r < 4; ++r) {
        int row = mt*16 + quad*4 + r, col = w*32 + nt*16 + colb;
        int n = n0 + row;
        float xv = (n < NRES) ? x[(size_t)n * 128 + col] : 0.0f;
        sA[row][col] = f2bf(xv + swish_fast(acc1[mt][nt][r]));
      }
  __syncthreads();

  // GEMM2: h = relu(xe@Wo0 + bo0)
  floatx4 acc2[4][2];
  #pragma unroll
  for (int mt = 0; mt < 4; ++mt) {
    acc2[mt][0] = (floatx4){0.f,0.f,0.f,0.f};
    acc2[mt][1] = (floatx4){0.f,0.f,0.f,0.f};
  }
  #pragma unroll
  for (int kt = 0; kt < 4; ++kt) {
    short8 b0 = *(const short8*)&Wo0f[(size_t)((kt*8 + w*2 + 0)*64 + lane)*8];
    short8 b1 = *(const short8*)&Wo0f[(size_t)((kt*8 + w*2 + 1)*64 + lane)*8];
    #pragma unroll
    for (int mt = 0; mt < 4; ++mt) {
      short8 a = *(const short8*)&sA[mt*16 + colb][kt*32 + quad*8];
      acc2[mt][0] = __builtin_amdgcn_mfma_f32_16x16x32_bf16(a, b0, acc2[mt][0], 0, 0, 0);
      acc2[mt][1] = __builtin_amdgcn_mfma_f32_16x16x32_bf16(a, b1, acc2[mt][1], 0, 0, 0);
    }
  }
  __syncthreads();   // all reads of sX done; safe to overwrite with h
  #pragma unroll
  for (int mt = 0; mt < 4; ++mt)
    #pragma unroll
    for (int nt = 0; nt < 2; ++nt) {
      int col = w*32 + nt*16 + colb;
      float bias = bo0[col];
      #pragma unroll
      for (int r = 0; r < 4; ++r) {
        int row = mt*16 + quad*4 + r;
        sX[row][col] = f2bf(fmaxf(acc2[mt][nt][r] + bias, 0.0f));
      }
    }
  __syncthreads();

  // GEMM3: h2 = relu(h@Wo1 + bo1); wave w handles mtile w
  {
    floatx4 accH[2];
    accH[0] = (floatx4){0.f,0.f,0.f,0.f}; accH[1] = (floatx4){0.f,0.f,0.f,0.f};
    #pragma unroll
    for (int kt = 0; kt < 4; ++kt) {
      short8 a = *(const short8*)&sX[w*16 + colb][kt*32 + quad*8];
      #pragma unroll
      for (int nt = 0; nt < 2; ++nt) {
        short8 bf = *(const short8*)&Wo1f[(size_t)((kt*2 + nt)*64 + lane)*8];
        accH[nt] = __builtin_amdgcn_mfma_f32_16x16x32_bf16(a, bf, accH[nt], 0, 0, 0);
      }
    }
    __syncthreads();   // out1 readers of sS are long done (barriers above)
    #pragma unroll
    for (int nt = 0; nt < 2; ++nt) {
      int col = nt*16 + colb;
      float bias = bo1[col];
      #pragma unroll
      for (int r = 0; r < 4; ++r)
        sS[w*16 + quad*4 + r][col] = fmaxf(accH[nt][r] + bias, 0.0f);
    }
  }
  __syncthreads();

  if (tid < 64) {
    int n = n0 + tid;
    if (n < NRES) {
      float a2 = bof[0];
      #pragma unroll
      for (int k = 0; k < 32; ++k) a2 += sS[tid][k] * Wof[k];
      out0[n] = 1.0f / (1.0f + expf(-a2));
    }
  }
}

// ---------------------------------------------------------------------------
extern "C" void kernel_launch(void* const* d_in, const int* in_sizes, int n_in,
                              void* d_out, int out_size, void* d_ws, size_t ws_size,
                              hipStream_t stream) {
  (void)in_sizes; (void)n_in; (void)out_size; (void)ws_size;
  const int*   z     = (const int*)  d_in[0];
  const float* pos   = (const float*)d_in[1];
  const float* posn  = (const float*)d_in[2];
  const float* posc  = (const float*)d_in[3];
  const float* bb    = (const float*)d_in[4];
  const float* side  = (const float*)d_in[5];
  const float* esm   = (const float*)d_in[6];
  const int*   ei    = (const int*)  d_in[8];
  const float* W_emb = (const float*)d_in[9];
  const float* b_emb = (const float*)d_in[10];
  const float* W_esm = (const float*)d_in[11];
  const float* b_esm = (const float*)d_in[12];
  const float* W_edge= (const float*)d_in[13];
  const float* W_msg = (const float*)d_in[14];
  const float* W_upd = (const float*)d_in[15];
  const float* W_o0  = (const float*)d_in[16];
  const float* b_o0  = (const float*)d_in[17];
  const float* W_o1  = (const float*)d_in[18];
  const float* b_o1  = (const float*)d_in[19];
  const float* W_of  = (const float*)d_in[20];
  const float* b_of  = (const float*)d_in[21];
  const float* W_n0  = (const float*)d_in[22];
  const float* b_n0  = (const float*)d_in[23];
  const float* W_nf  = (const float*)d_in[24];
  const float* b_nf  = (const float*)d_in[25];

  char* ws = (char*)d_ws;
  float* x    = (float*)ws;                            // 25,600,000 B
  float* agg  = (float*)(ws + 25600000);               // 25,600,000 B
  short* Wef  = (short*)(ws + 51200000);               // 32,768 B
  short* Wmf  = (short*)(ws + 51232768);               // 32,768 B
  short* Wsf  = (short*)(ws + 51265536);               // 163,840 B
  short* Wuf  = (short*)(ws + 51429376);               // 32,768 B
  short* Wo0f = (short*)(ws + 51462144);               // 32,768 B
  short* Wn0f = (short*)(ws + 51494912);               // 8,192 B
  short* Wo1f = (short*)(ws + 51503104);               // 8,192 B
  float* out0 = (float*)d_out;                         // [N]
  float* out1 = out0 + NRES;                           // [N,2]

  hipMemsetAsync(agg, 0, (size_t)NRES * 128 * sizeof(float), stream);

  k_wprep<<<608, 256, 0, stream>>>(W_edge, W_msg, W_esm, W_upd, W_o0, W_n0, W_o1,
                                   Wef, Wmf, Wsf, Wuf, Wo0f, Wn0f, Wo1f);
  k_xa   <<<12500, 256, 0, stream>>>(z, bb, side, W_emb, b_emb, x);
  k_esm  <<<782,   256, 0, stream>>>(esm, Wsf, b_esm, x);
  k_edge <<<15625, 256, 0, stream>>>(ei, pos, posn, posc, x, Wef, Wmf, agg);
  k_upd  <<<782,   256, 0, stream>>>(x, agg, Wuf, Wo0f, Wn0f, Wo1f,
                                     b_n0, W_nf, b_nf, b_o0, b_o1, W_of, b_of,
                                     out0, out1);
}

// Round 4
// 735.335 us; speedup vs baseline: 4.7505x; 1.2024x over previous
//
#include <hip/hip_runtime.h>
#include <math.h>
#include <stdint.h>

#define NRES 50000
#define NEDGE 1000000
#define PI_F 3.14159265358979323846f

typedef __attribute__((ext_vector_type(8))) short short8;
typedef __attribute__((ext_vector_type(4))) float floatx4;
typedef __attribute__((ext_vector_type(2))) short bf16x2;
typedef __attribute__((address_space(1))) bf16x2* gbf16x2p;

struct f3 { float x, y, z; };
__device__ __forceinline__ f3 ld3(const float* __restrict__ p, int i) {
  return {p[3*i+0], p[3*i+1], p[3*i+2]};
}
__device__ __forceinline__ f3 f3sub(f3 a, f3 b){ return {a.x-b.x, a.y-b.y, a.z-b.z}; }
__device__ __forceinline__ f3 f3cross(f3 a, f3 b){
  return {a.y*b.z - a.z*b.y, a.z*b.x - a.x*b.z, a.x*b.y - a.y*b.x};
}
__device__ __forceinline__ float f3dot(f3 a, f3 b){ return a.x*b.x + a.y*b.y + a.z*b.z; }
__device__ __forceinline__ float swish_fast(float v){
  return v * __builtin_amdgcn_rcpf(1.0f + __expf(-v));
}
__device__ __forceinline__ short f2bf(float f){
  unsigned u = __float_as_uint(f);
  unsigned r = (u + 0x7fffu + ((u >> 16) & 1u)) >> 16;
  return (short)r;
}
__device__ __forceinline__ float cos_atan2(float y, float x){
  return x * __builtin_amdgcn_rsqf(fmaxf(x*x + y*y, 1e-30f));
}
// packed bf16 atomic add (global_atomic_pk_add_bf16)
__device__ __forceinline__ void atom_pk_bf16(short* addr, bf16x2 v){
  __builtin_amdgcn_global_atomic_fadd_v2bf16((gbf16x2p)(uintptr_t)addr, v);
}

// ---------------------------------------------------------------------------
// weight prep -> bf16 MFMA B-fragment order.
__global__ __launch_bounds__(256) void k_wprep(
    const float* __restrict__ We, const float* __restrict__ Wm,
    const float* __restrict__ Ws, const float* __restrict__ Wu,
    const float* __restrict__ Wo0, const float* __restrict__ Wn0,
    const float* __restrict__ Wo1,
    short* __restrict__ Wef, short* __restrict__ Wmf, short* __restrict__ Wsf,
    short* __restrict__ Wuf, short* __restrict__ Wo0f,
    short* __restrict__ Wn0f, short* __restrict__ Wo1f)
{
  int gid = blockIdx.x * 256 + threadIdx.x;
  const float* src; short* dst; int NT, K, N, t;
  if      (gid < 16384)  { t = gid;          src = We;  dst = Wef;  NT = 8; K = 124;  N = 128; }
  else if (gid < 32768)  { t = gid - 16384;  src = Wm;  dst = Wmf;  NT = 8; K = 128;  N = 128; }
  else if (gid < 114688) { t = gid - 32768;  src = Ws;  dst = Wsf;  NT = 4; K = 1280; N = 64;  }
  else if (gid < 131072) { t = gid - 114688; src = Wu;  dst = Wuf;  NT = 8; K = 128;  N = 128; }
  else if (gid < 147456) { t = gid - 131072; src = Wo0; dst = Wo0f; NT = 8; K = 128;  N = 128; }
  else if (gid < 151552) { t = gid - 147456; src = Wn0; dst = Wn0f; NT = 2; K = 128;  N = 32;  }
  else if (gid < 155648) { t = gid - 151552; src = Wo1; dst = Wo1f; NT = 2; K = 128;  N = 32;  }
  else return;
  int j = t & 7, lane = (t >> 3) & 63;
  int rest = t >> 9;
  int nt = rest % NT, kt = rest / NT;
  int k = kt*32 + (lane >> 4)*8 + j, n = nt*16 + (lane & 15);
  dst[t] = f2bf((k < K) ? src[k*N + n] : 0.0f);
}

// ---------------------------------------------------------------------------
// x_a -> x[:,0:64] (f32) and xb[:,0:64] (bf16)
__global__ __launch_bounds__(256) void k_xa(
    const int* __restrict__ z, const float* __restrict__ bb,
    const float* __restrict__ side, const float* __restrict__ W_emb,
    const float* __restrict__ b_emb, float* __restrict__ x,
    short* __restrict__ xb)
{
  int tid = threadIdx.x;
  int h = tid & 63;
  int n = blockIdx.x * 4 + (tid >> 6);
  if (n >= NRES) return;
  int zz = z[n];
  float acc = W_emb[zz * 64 + h] + b_emb[h];
  #pragma unroll
  for (int k = 0; k < 6; ++k) acc += bb[n*6 + k] * W_emb[(26 + k)*64 + h];
  #pragma unroll
  for (int k = 0; k < 8; ++k) acc += side[n*8 + k] * W_emb[(32 + k)*64 + h];
  x[(size_t)n * 128 + h] = acc;
  xb[(size_t)n * 128 + h] = f2bf(acc);
}

// ---------------------------------------------------------------------------
// x_s = esm @ W_esm + b -> x[:,64:128] (f32) and xb[:,64:128] (bf16)
__global__ __launch_bounds__(256) void k_esm(
    const float* __restrict__ esm, const short* __restrict__ Wsf,
    const float* __restrict__ b, float* __restrict__ x,
    short* __restrict__ xb)
{
  __shared__ __align__(16) short sA[64][136];
  const int tid = threadIdx.x;
  const int lane = tid & 63, w = tid >> 6;
  const int quad = lane >> 4, colb = lane & 15;
  const int n0 = blockIdx.x * 64;

  floatx4 acc[4];
  #pragma unroll
  for (int nt = 0; nt < 4; ++nt) acc[nt] = (floatx4){0.f, 0.f, 0.f, 0.f};

  for (int kc = 0; kc < 10; ++kc) {
    #pragma unroll
    for (int it = 0; it < 8; ++it) {
      int idx = it * 256 + tid;
      int row = idx >> 5, c4 = idx & 31;
      int n = n0 + row;
      float4 v = make_float4(0.f, 0.f, 0.f, 0.f);
      if (n < NRES) v = *(const float4*)&esm[(size_t)n * 1280 + kc*128 + c4*4];
      short* dst = &sA[row][c4*4];
      dst[0] = f2bf(v.x); dst[1] = f2bf(v.y);
      dst[2] = f2bf(v.z); dst[3] = f2bf(v.w);
    }
    __syncthreads();
    #pragma unroll
    for (int kt = 0; kt < 4; ++kt) {
      int gkt = kc*4 + kt;
      short8 a = *(const short8*)&sA[w*16 + colb][kt*32 + quad*8];
      #pragma unroll
      for (int nt = 0; nt < 4; ++nt) {
        short8 bf = *(const short8*)&Wsf[(size_t)((gkt*4 + nt)*64 + lane)*8];
        acc[nt] = __builtin_amdgcn_mfma_f32_16x16x32_bf16(a, bf, acc[nt], 0, 0, 0);
      }
    }
    __syncthreads();
  }
  #pragma unroll
  for (int nt = 0; nt < 4; ++nt) {
    int ch = nt*16 + colb;
    float bias = b[ch];
    #pragma unroll
    for (int r = 0; r < 4; ++r) {
      int n = n0 + w*16 + quad*4 + r;
      if (n < NRES) {
        float val = acc[nt][r] + bias;
        x [(size_t)n * 128 + 64 + ch] = val;
        xb[(size_t)n * 128 + 64 + ch] = f2bf(val);
      }
    }
  }
}

// ---------------------------------------------------------------------------
// edge kernel (MFMA): 64 edges/block, 256 threads = 4 waves.
// wave 0: geometry -> sF bf16; waves 1-3: gather xb[j] -> sXJ.
// Dual GEMM; epilogue stages m (bf16) in LDS, then coalesced packed-bf16
// atomics into aggb[i].
__global__ __launch_bounds__(256, 4) void k_edge(
    const int* __restrict__ ei, const float* __restrict__ pos,
    const float* __restrict__ posn, const float* __restrict__ posc,
    const short* __restrict__ xb, const short* __restrict__ Wef,
    const short* __restrict__ Wmf, short* __restrict__ aggb)
{
  __shared__ int sJ[64];
  __shared__ int sI[64];
  __shared__ __align__(16) short sF[64][136];
  __shared__ __align__(16) short sXJ[64][136];

  const int tid = threadIdx.x;
  const int e0 = blockIdx.x * 64;

  if (tid < 64) { sJ[tid] = ei[e0 + tid]; sI[tid] = ei[NEDGE + e0 + tid]; }
  __syncthreads();

  if (tid < 64) {
    const int e = tid;
    const int j = sJ[e], i = sI[e];
    f3 pj = ld3(pos, j), pi = ld3(pos, i);
    f3 vji = f3sub(pj, pi);
    float nji2 = f3dot(vji, vji);
    float dist = sqrtf(nji2);
    int r0i = (i == 0) ? (NRES - 1) : (i - 1);
    int r1i = (i == NRES - 1) ? 0 : (i + 1);
    f3 vr0 = f3sub(ld3(pos, r0i), pi);
    f3 vr1 = f3sub(ld3(pos, r1i), pi);
    float nr02 = f3dot(vr0, vr0);

    float ct = f3dot(vji, vr0) * __builtin_amdgcn_rsqf(fmaxf(nji2 * nr02, 1e-30f));
    f3 p1 = f3cross(vr0, vr1);
    f3 p2 = f3cross(vr0, vji);
    float pa = f3dot(p1, p2);
    float pb = f3dot(f3cross(p1, p2), vr0) / (sqrtf(nr02) + 1e-7f);
    float cp = cos_atan2(pb, pa);

    f3 pni = ld3(posn, i), pci = ld3(posc, i);
    f3 o1x = f3sub(pni, pi);
    f3 o1z = f3cross(o1x, f3cross(o1x, f3sub(pci, pi)));
    float no1z2 = f3dot(o1z, o1z);
    float o1zl = sqrtf(no1z2) + 1e-7f;
    f3 pnj = ld3(posn, j), pcj = ld3(posc, j);
    f3 o2x = f3sub(pnj, pj);
    f3 o2z = f3cross(o2x, f3cross(o2x, f3sub(pcj, pj)));
    float no2z2 = f3dot(o2z, o2z);
    float o2zl = sqrtf(no2z2) + 1e-7f;
    f3 nv = f3cross(o1z, o2z);
    float y1 = f3dot(f3cross(o1x, nv), o1z) / o1zl;
    float ca1 = cos_atan2(y1, f3dot(o1x, nv));
    float ca2 = f3dot(o1z, o2z) * __builtin_amdgcn_rsqf(fmaxf(no1z2 * no2z2, 1e-30f));
    float y3 = f3dot(f3cross(nv, o2x), o2z) / o2zl;
    float ca3 = cos_atan2(y3, f3dot(nv, o2x));

    float u = fminf(dist * (1.0f/11.5f), 1.0f);
    float spu, cpu;
    __sincosf(PI_F * u, &spu, &cpu);
    float fc = 0.5f * (cpu + 1.0f);
    float pref = 0.41702882811414954f * __builtin_amdgcn_rcpf(dist + 1e-6f) * fc;
    float rb[6];
    {
      float twoc = 2.0f * cpu;
      float s_nm1 = 0.0f, s_n = spu;
      #pragma unroll
      for (int nn = 0; nn < 6; ++nn) {
        rb[nn] = pref * s_n;
        float s_np1 = twoc * s_n - s_nm1;
        s_nm1 = s_n; s_n = s_np1;
      }
    }

    float ctv[3] = {1.0f, ct, 2.0f*ct*ct - 1.0f};
    float cpv[3] = {1.0f, cp, 2.0f*cp*cp - 1.0f};
    #pragma unroll
    for (int nn = 0; nn < 6; ++nn)
      #pragma unroll
      for (int l = 0; l < 3; ++l)
        #pragma unroll
        for (int m = 0; m < 3; ++m)
          sF[e][nn*9 + l*3 + m] = f2bf(rb[nn] * ctv[l] * cpv[m]);

    float cas[3] = {ca1, ca2, ca3};
    #pragma unroll
    for (int t = 0; t < 3; ++t) {
      float c = cas[t];
      float cav[3] = {1.0f, c, 2.0f*c*c - 1.0f};
      #pragma unroll
      for (int nn = 0; nn < 6; ++nn)
        #pragma unroll
        for (int l = 0; l < 3; ++l)
          sF[e][54 + t*18 + nn*3 + l] = f2bf(rb[nn] * cav[l]);
    }

    const float FRQ[8] = {1.0f, 0.31622776601683794f, 0.1f, 0.03162277660168379f,
                          0.01f, 0.003162277660168379f, 0.001f, 0.0003162277660168379f};
    float dpe = (float)(j - i);
    #pragma unroll
    for (int q = 0; q < 8; ++q) {
      float s, c;
      __sincosf(dpe * FRQ[q], &s, &c);
      sF[e][108 + q] = f2bf(c);
      sF[e][116 + q] = f2bf(s);
    }
    sF[e][124] = 0; sF[e][125] = 0; sF[e][126] = 0; sF[e][127] = 0;
  } else {
    // threads 64..255 gather xb[j] (bf16): 64 rows x 16 short8 = 1024
    const int t2 = tid - 64;
    for (int it = 0; it < 6; ++it) {
      int idx = it * 192 + t2;
      if (idx < 1024) {
        int row = idx >> 4;
        int c8 = idx & 15;
        *(short8*)&sXJ[row][c8*8] = *(const short8*)&xb[(size_t)sJ[row] * 128 + c8*8];
      }
    }
  }
  __syncthreads();

  const int lane = tid & 63, w = tid >> 6;
  const int quad = lane >> 4, colb = lane & 15;
  const int nb = w * 2;

  short8 bE[4][2], bM[4][2];
  #pragma unroll
  for (int kt = 0; kt < 4; ++kt)
    #pragma unroll
    for (int nt = 0; nt < 2; ++nt) {
      bE[kt][nt] = *(const short8*)&Wef[(size_t)((kt*8 + nb + nt)*64 + lane)*8];
      bM[kt][nt] = *(const short8*)&Wmf[(size_t)((kt*8 + nb + nt)*64 + lane)*8];
    }

  floatx4 accE[4][2], accM[4][2];
  #pragma unroll
  for (int mt = 0; mt < 4; ++mt)
    #pragma unroll
    for (int nt = 0; nt < 2; ++nt) {
      accE[mt][nt] = (floatx4){0.f, 0.f, 0.f, 0.f};
      accM[mt][nt] = (floatx4){0.f, 0.f, 0.f, 0.f};
    }

  #pragma unroll
  for (int kt = 0; kt < 4; ++kt) {
    #pragma unroll
    for (int mt = 0; mt < 4; ++mt) {
      short8 af = *(const short8*)&sF [mt*16 + colb][kt*32 + quad*8];
      short8 ax = *(const short8*)&sXJ[mt*16 + colb][kt*32 + quad*8];
      #pragma unroll
      for (int nt = 0; nt < 2; ++nt) {
        accE[mt][nt] = __builtin_amdgcn_mfma_f32_16x16x32_bf16(af, bE[kt][nt], accE[mt][nt], 0, 0, 0);
        accM[mt][nt] = __builtin_amdgcn_mfma_f32_16x16x32_bf16(ax, bM[kt][nt], accM[mt][nt], 0, 0, 0);
      }
    }
  }
  __syncthreads();   // all LDS reads done; reuse sXJ as m-staging

  short (*sM)[136] = sXJ;
  #pragma unroll
  for (int mt = 0; mt < 4; ++mt)
    #pragma unroll
    for (int nt = 0; nt < 2; ++nt) {
      int ch = w*32 + nt*16 + colb;
      #pragma unroll
      for (int r = 0; r < 4; ++r) {
        int e = mt*16 + quad*4 + r;
        sM[e][ch] = f2bf(swish_fast(accM[mt][nt][r]) * swish_fast(accE[mt][nt][r]));
      }
    }
  __syncthreads();

  // coalesced packed-bf16 atomics: one full row (256 B) per wave-instr
  #pragma unroll
  for (int it = 0; it < 16; ++it) {
    int flat = it * 256 + tid;        // 0..4095
    int row = flat >> 6, p = flat & 63;
    bf16x2 v = *(const bf16x2*)&sM[row][p*2];
    atom_pk_bf16(&aggb[(size_t)sI[row] * 128 + p*2], v);
  }
}

// ---------------------------------------------------------------------------
// fused update + both heads (MFMA). 64 nodes/block, 256 threads = 4 waves.
__global__ __launch_bounds__(256) void k_upd(
    const float* __restrict__ x, const short* __restrict__ xb,
    const short* __restrict__ aggb,
    const short* __restrict__ Wuf, const short* __restrict__ Wo0f,
    const short* __restrict__ Wn0f, const short* __restrict__ Wo1f,
    const float* __restrict__ bn0, const float* __restrict__ Wnf,
    const float* __restrict__ bnf, const float* __restrict__ bo0,
    const float* __restrict__ bo1, const float* __restrict__ Wof,
    const float* __restrict__ bof, float* __restrict__ out0,
    float* __restrict__ out1)
{
  __shared__ __align__(16) short sA[64][136];   // aggb -> xe bf16
  __shared__ __align__(16) short sX[64][136];   // xb   -> h  bf16
  __shared__ float sS[64][33];                  // hn / h2 scratch (f32)

  const int tid = threadIdx.x;
  const int lane = tid & 63, w = tid >> 6;
  const int quad = lane >> 4, colb = lane & 15;
  const int n0 = blockIdx.x * 64;

  #pragma unroll
  for (int it = 0; it < 4; ++it) {
    int idx = it * 256 + tid;        // 0..1023
    int row = idx >> 4, c8 = idx & 15;
    int n = n0 + row;
    short8 va = (short8)(short)0, vx = (short8)(short)0;
    if (n < NRES) {
      va = *(const short8*)&aggb[(size_t)n * 128 + c8*8];
      vx = *(const short8*)&xb  [(size_t)n * 128 + c8*8];
    }
    *(short8*)&sA[row][c8*8] = va;
    *(short8*)&sX[row][c8*8] = vx;
  }
  __syncthreads();

  // hn = relu(x@Wn0+bn0); wave w handles mtile w
  {
    floatx4 accN[2];
    accN[0] = (floatx4){0.f,0.f,0.f,0.f}; accN[1] = (floatx4){0.f,0.f,0.f,0.f};
    #pragma unroll
    for (int kt = 0; kt < 4; ++kt) {
      short8 a = *(const short8*)&sX[w*16 + colb][kt*32 + quad*8];
      #pragma unroll
      for (int nt = 0; nt < 2; ++nt) {
        short8 bf = *(const short8*)&Wn0f[(size_t)((kt*2 + nt)*64 + lane)*8];
        accN[nt] = __builtin_amdgcn_mfma_f32_16x16x32_bf16(a, bf, accN[nt], 0, 0, 0);
      }
    }
    #pragma unroll
    for (int nt = 0; nt < 2; ++nt) {
      int col = nt*16 + colb;
      float bias = bn0[col];
      #pragma unroll
      for (int r = 0; r < 4; ++r)
        sS[w*16 + quad*4 + r][col] = fmaxf(accN[nt][r] + bias, 0.0f);
    }
  }
  __syncthreads();
  if (tid < 128) {
    int row = tid >> 1, oc = tid & 1;
    int n = n0 + row;
    if (n < NRES) {
      float a2 = bnf[oc];
      #pragma unroll
      for (int k = 0; k < 32; ++k) a2 += sS[row][k] * Wnf[k*2 + oc];
      out1[(size_t)n * 2 + oc] = a2;
    }
  }

  // GEMM1: t = agg@Wu
  floatx4 acc1[4][2];
  #pragma unroll
  for (int mt = 0; mt < 4; ++mt) {
    acc1[mt][0] = (floatx4){0.f,0.f,0.f,0.f};
    acc1[mt][1] = (floatx4){0.f,0.f,0.f,0.f};
  }
  #pragma unroll
  for (int kt = 0; kt < 4; ++kt) {
    short8 b0 = *(const short8*)&Wuf[(size_t)((kt*8 + w*2 + 0)*64 + lane)*8];
    short8 b1 = *(const short8*)&Wuf[(size_t)((kt*8 + w*2 + 1)*64 + lane)*8];
    #pragma unroll
    for (int mt = 0; mt < 4; ++mt) {
      short8 a = *(const short8*)&sA[mt*16 + colb][kt*32 + quad*8];
      acc1[mt][0] = __builtin_amdgcn_mfma_f32_16x16x32_bf16(a, b0, acc1[mt][0], 0, 0, 0);
      acc1[mt][1] = __builtin_amdgcn_mfma_f32_16x16x32_bf16(a, b1, acc1[mt][1], 0, 0, 0);
    }
  }
  __syncthreads();
  #pragma unroll
  for (int mt = 0; mt < 4; ++mt)
    #pragma unroll
    for (int nt = 0; nt < 2; ++nt)
      #pragma unroll
      for (int r = 0; r < 4; ++r) {
        int row = mt*16 + quad*4 + r, col = w*32 + nt*16 + colb;
        int n = n0 + row;
        float xv = (n < NRES) ? x[(size_t)n * 128 + col] : 0.0f;
        sA[row][col] = f2bf(xv + swish_fast(acc1[mt][nt][r]));
      }
  __syncthreads();

  // GEMM2: h = relu(xe@Wo0 + bo0)
  floatx4 acc2[4][2];
  #pragma unroll
  for (int mt = 0; mt < 4; ++mt) {
    acc2[mt][0] = (floatx4){0.f,0.f,0.f,0.f};
    acc2[mt][1] = (floatx4){0.f,0.f,0.f,0.f};
  }
  #pragma unroll
  for (int kt = 0; kt < 4; ++kt) {
    short8 b0 = *(const short8*)&Wo0f[(size_t)((kt*8 + w*2 + 0)*64 + lane)*8];
    short8 b1 = *(const short8*)&Wo0f[(size_t)((kt*8 + w*2 + 1)*64 + lane)*8];
    #pragma unroll
    for (int mt = 0; mt < 4; ++mt) {
      short8 a = *(const short8*)&sA[mt*16 + colb][kt*32 + quad*8];
      acc2[mt][0] = __builtin_amdgcn_mfma_f32_16x16x32_bf16(a, b0, acc2[mt][0], 0, 0, 0);
      acc2[mt][1] = __builtin_amdgcn_mfma_f32_16x16x32_bf16(a, b1, acc2[mt][1], 0, 0, 0);
    }
  }
  __syncthreads();
  #pragma unroll
  for (int mt = 0; mt < 4; ++mt)
    #pragma unroll
    for (int nt = 0; nt < 2; ++nt) {
      int col = w*32 + nt*16 + colb;
      float bias = bo0[col];
      #pragma unroll
      for (int r = 0; r < 4; ++r) {
        int row = mt*16 + quad*4 + r;
        sX[row][col] = f2bf(fmaxf(acc2[mt][nt][r] + bias, 0.0f));
      }
    }
  __syncthreads();

  // GEMM3: h2 = relu(h@Wo1 + bo1); wave w handles mtile w
  {
    floatx4 accH[2];
    accH[0] = (floatx4){0.f,0.f,0.f,0.f}; accH[1] = (floatx4){0.f,0.f,0.f,0.f};
    #pragma unroll
    for (int kt = 0; kt < 4; ++kt) {
      short8 a = *(const short8*)&sX[w*16 + colb][kt*32 + quad*8];
      #pragma unroll
      for (int nt = 0; nt < 2; ++nt) {
        short8 bf = *(const short8*)&Wo1f[(size_t)((kt*2 + nt)*64 + lane)*8];
        accH[nt] = __builtin_amdgcn_mfma_f32_16x16x32_bf16(a, bf, accH[nt], 0, 0, 0);
      }
    }
    __syncthreads();
    #pragma unroll
    for (int nt = 0; nt < 2; ++nt) {
      int col = nt*16 + colb;
      float bias = bo1[col];
      #pragma unroll
      for (int r = 0; r < 4; ++r)
        sS[w*16 + quad*4 + r][col] = fmaxf(accH[nt][r] + bias, 0.0f);
    }
  }
  __syncthreads();

  if (tid < 64) {
    int n = n0 + tid;
    if (n < NRES) {
      float a2 = bof[0];
      #pragma unroll
      for (int k = 0; k < 32; ++k) a2 += sS[tid][k] * Wof[k];
      out0[n] = 1.0f / (1.0f + expf(-a2));
    }
  }
}

// ---------------------------------------------------------------------------
extern "C" void kernel_launch(void* const* d_in, const int* in_sizes, int n_in,
                              void* d_out, int out_size, void* d_ws, size_t ws_size,
                              hipStream_t stream) {
  (void)in_sizes; (void)n_in; (void)out_size; (void)ws_size;
  const int*   z     = (const int*)  d_in[0];
  const float* pos   = (const float*)d_in[1];
  const float* posn  = (const float*)d_in[2];
  const float* posc  = (const float*)d_in[3];
  const float* bb    = (const float*)d_in[4];
  const float* side  = (const float*)d_in[5];
  const float* esm   = (const float*)d_in[6];
  const int*   ei    = (const int*)  d_in[8];
  const float* W_emb = (const float*)d_in[9];
  const float* b_emb = (const float*)d_in[10];
  const float* W_esm = (const float*)d_in[11];
  const float* b_esm = (const float*)d_in[12];
  const float* W_edge= (const float*)d_in[13];
  const float* W_msg = (const float*)d_in[14];
  const float* W_upd = (const float*)d_in[15];
  const float* W_o0  = (const float*)d_in[16];
  const float* b_o0  = (const float*)d_in[17];
  const float* W_o1  = (const float*)d_in[18];
  const float* b_o1  = (const float*)d_in[19];
  const float* W_of  = (const float*)d_in[20];
  const float* b_of  = (const float*)d_in[21];
  const float* W_n0  = (const float*)d_in[22];
  const float* b_n0  = (const float*)d_in[23];
  const float* W_nf  = (const float*)d_in[24];
  const float* b_nf  = (const float*)d_in[25];

  char* ws = (char*)d_ws;
  float* x    = (float*)ws;                            // 25,600,000 B
  short* xb   = (short*)(ws + 25600000);               // 12,800,000 B
  short* aggb = (short*)(ws + 38400000);               // 12,800,000 B
  short* Wef  = (short*)(ws + 51200000);               // 32,768 B
  short* Wmf  = (short*)(ws + 51232768);               // 32,768 B
  short* Wsf  = (short*)(ws + 51265536);               // 163,840 B
  short* Wuf  = (short*)(ws + 51429376);               // 32,768 B
  short* Wo0f = (short*)(ws + 51462144);               // 32,768 B
  short* Wn0f = (short*)(ws + 51494912);               // 8,192 B
  short* Wo1f = (short*)(ws + 51503104);               // 8,192 B
  float* out0 = (float*)d_out;                         // [N]
  float* out1 = out0 + NRES;                           // [N,2]

  hipMemsetAsync(aggb, 0, (size_t)NRES * 128 * sizeof(short), stream);

  k_wprep<<<608, 256, 0, stream>>>(W_edge, W_msg, W_esm, W_upd, W_o0, W_n0, W_o1,
                                   Wef, Wmf, Wsf, Wuf, Wo0f, Wn0f, Wo1f);
  k_xa   <<<12500, 256, 0, stream>>>(z, bb, side, W_emb, b_emb, x, xb);
  k_esm  <<<782,   256, 0, stream>>>(esm, Wsf, b_esm, x, xb);
  k_edge <<<15625, 256, 0, stream>>>(ei, pos, posn, posc, xb, Wef, Wmf, aggb);
  k_upd  <<<782,   256, 0, stream>>>(x, xb, aggb, Wuf, Wo0f, Wn0f, Wo1f,
                                     b_n0, W_nf, b_nf, b_o0, b_o1, W_of, b_of,
                                     out0, out1);
}

// Round 5
// 713.478 us; speedup vs baseline: 4.8961x; 1.0306x over previous
//
#include <hip/hip_runtime.h>
#include <math.h>
#include <stdint.h>

#define NRES 50000
#define NEDGE 1000000
#define PI_F 3.14159265358979323846f

typedef __attribute__((ext_vector_type(8))) short short8;
typedef __attribute__((ext_vector_type(4))) float floatx4;
typedef __attribute__((ext_vector_type(2))) short bf16x2;
typedef __attribute__((address_space(1))) bf16x2* gbf16x2p;

struct f3 { float x, y, z; };
__device__ __forceinline__ f3 ld3(const float* __restrict__ p, int i) {
  return {p[3*i+0], p[3*i+1], p[3*i+2]};
}
__device__ __forceinline__ f3 f3sub(f3 a, f3 b){ return {a.x-b.x, a.y-b.y, a.z-b.z}; }
__device__ __forceinline__ f3 f3cross(f3 a, f3 b){
  return {a.y*b.z - a.z*b.y, a.z*b.x - a.x*b.z, a.x*b.y - a.y*b.x};
}
__device__ __forceinline__ float f3dot(f3 a, f3 b){ return a.x*b.x + a.y*b.y + a.z*b.z; }
__device__ __forceinline__ float swish_fast(float v){
  return v * __builtin_amdgcn_rcpf(1.0f + __expf(-v));
}
__device__ __forceinline__ short f2bf(float f){
  unsigned u = __float_as_uint(f);
  unsigned r = (u + 0x7fffu + ((u >> 16) & 1u)) >> 16;
  return (short)r;
}
__device__ __forceinline__ float bf2f(short s){
  return __uint_as_float(((unsigned)(unsigned short)s) << 16);
}
__device__ __forceinline__ float cos_atan2(float y, float x){
  return x * __builtin_amdgcn_rsqf(fmaxf(x*x + y*y, 1e-30f));
}
__device__ __forceinline__ void atom_pk_bf16(short* addr, bf16x2 v){
  __builtin_amdgcn_global_atomic_fadd_v2bf16((gbf16x2p)(uintptr_t)addr, v);
}

// ---------------------------------------------------------------------------
// weight prep -> bf16 MFMA B-fragment order.
__global__ __launch_bounds__(256) void k_wprep(
    const float* __restrict__ We, const float* __restrict__ Wm,
    const float* __restrict__ Ws, const float* __restrict__ Wu,
    const float* __restrict__ Wo0, const float* __restrict__ Wn0,
    const float* __restrict__ Wo1,
    short* __restrict__ Wef, short* __restrict__ Wmf, short* __restrict__ Wsf,
    short* __restrict__ Wuf, short* __restrict__ Wo0f,
    short* __restrict__ Wn0f, short* __restrict__ Wo1f)
{
  int gid = blockIdx.x * 256 + threadIdx.x;
  const float* src; short* dst; int NT, K, N, t;
  if      (gid < 16384)  { t = gid;          src = We;  dst = Wef;  NT = 8; K = 124;  N = 128; }
  else if (gid < 32768)  { t = gid - 16384;  src = Wm;  dst = Wmf;  NT = 8; K = 128;  N = 128; }
  else if (gid < 114688) { t = gid - 32768;  src = Ws;  dst = Wsf;  NT = 4; K = 1280; N = 64;  }
  else if (gid < 131072) { t = gid - 114688; src = Wu;  dst = Wuf;  NT = 8; K = 128;  N = 128; }
  else if (gid < 147456) { t = gid - 131072; src = Wo0; dst = Wo0f; NT = 8; K = 128;  N = 128; }
  else if (gid < 151552) { t = gid - 147456; src = Wn0; dst = Wn0f; NT = 2; K = 128;  N = 32;  }
  else if (gid < 155648) { t = gid - 151552; src = Wo1; dst = Wo1f; NT = 2; K = 128;  N = 32;  }
  else return;
  int j = t & 7, lane = (t >> 3) & 63;
  int rest = t >> 9;
  int nt = rest % NT, kt = rest / NT;
  int k = kt*32 + (lane >> 4)*8 + j, n = nt*16 + (lane & 15);
  dst[t] = f2bf((k < K) ? src[k*N + n] : 0.0f);
}

// ---------------------------------------------------------------------------
// x_a -> xb[:,0:64] (bf16 only)
__global__ __launch_bounds__(256) void k_xa(
    const int* __restrict__ z, const float* __restrict__ bb,
    const float* __restrict__ side, const float* __restrict__ W_emb,
    const float* __restrict__ b_emb, short* __restrict__ xb)
{
  int tid = threadIdx.x;
  int h = tid & 63;
  int n = blockIdx.x * 4 + (tid >> 6);
  if (n >= NRES) return;
  int zz = z[n];
  float acc = W_emb[zz * 64 + h] + b_emb[h];
  #pragma unroll
  for (int k = 0; k < 6; ++k) acc += bb[n*6 + k] * W_emb[(26 + k)*64 + h];
  #pragma unroll
  for (int k = 0; k < 8; ++k) acc += side[n*8 + k] * W_emb[(32 + k)*64 + h];
  xb[(size_t)n * 128 + h] = f2bf(acc);
}

// ---------------------------------------------------------------------------
// x_s = esm @ W_esm + b -> xb[:,64:128]  (barrier-free streaming MFMA)
// 256 threads = 4 waves, wave w owns rows [blk*64 + w*16, +16) x 64 cols.
// Lane loads its own A-fragment from global: row = tile0 + (lane&15),
// k-chunk = quad*8. Lanes {l, l+16, l+32, l+48} cover 128 contiguous bytes
// of one row per k-step -> single coalesced pass over esm. No LDS, no
// __syncthreads -> compiler pipelines loads across k-steps.
__global__ __launch_bounds__(256) void k_esm(
    const float* __restrict__ esm, const short* __restrict__ Wsf,
    const float* __restrict__ b, short* __restrict__ xb)
{
  const int tid = threadIdx.x;
  const int lane = tid & 63, w = tid >> 6;
  const int quad = lane >> 4, colb = lane & 15;
  const int tile0 = blockIdx.x * 64 + w * 16;

  int arow = tile0 + colb;
  if (arow >= NRES) arow = NRES - 1;          // clamp (dup read, store masked)
  const float* ap = esm + (size_t)arow * 1280 + quad * 8;

  floatx4 acc[4];
  #pragma unroll
  for (int nt = 0; nt < 4; ++nt) acc[nt] = (floatx4){0.f, 0.f, 0.f, 0.f};

  for (int kt = 0; kt < 40; ++kt) {
    float4 v0 = *(const float4*)(ap + kt*32);
    float4 v1 = *(const float4*)(ap + kt*32 + 4);
    short8 a;
    a[0] = f2bf(v0.x); a[1] = f2bf(v0.y); a[2] = f2bf(v0.z); a[3] = f2bf(v0.w);
    a[4] = f2bf(v1.x); a[5] = f2bf(v1.y); a[6] = f2bf(v1.z); a[7] = f2bf(v1.w);
    #pragma unroll
    for (int nt = 0; nt < 4; ++nt) {
      short8 bf = *(const short8*)&Wsf[(size_t)((kt*4 + nt)*64 + lane)*8];
      acc[nt] = __builtin_amdgcn_mfma_f32_16x16x32_bf16(a, bf, acc[nt], 0, 0, 0);
    }
  }
  #pragma unroll
  for (int nt = 0; nt < 4; ++nt) {
    int ch = nt*16 + colb;
    float bias = b[ch];
    #pragma unroll
    for (int r = 0; r < 4; ++r) {
      int n = tile0 + quad*4 + r;
      if (n < NRES) xb[(size_t)n * 128 + 64 + ch] = f2bf(acc[nt][r] + bias);
    }
  }
}

// ---------------------------------------------------------------------------
// edge kernel (MFMA): 64 edges/block, 256 threads = 4 waves.
__global__ __launch_bounds__(256, 4) void k_edge(
    const int* __restrict__ ei, const float* __restrict__ pos,
    const float* __restrict__ posn, const float* __restrict__ posc,
    const short* __restrict__ xb, const short* __restrict__ Wef,
    const short* __restrict__ Wmf, short* __restrict__ aggb)
{
  __shared__ int sJ[64];
  __shared__ int sI[64];
  __shared__ __align__(16) short sF[64][136];
  __shared__ __align__(16) short sXJ[64][136];

  const int tid = threadIdx.x;
  const int e0 = blockIdx.x * 64;

  if (tid < 64) { sJ[tid] = ei[e0 + tid]; sI[tid] = ei[NEDGE + e0 + tid]; }
  __syncthreads();

  if (tid < 64) {
    const int e = tid;
    const int j = sJ[e], i = sI[e];
    f3 pj = ld3(pos, j), pi = ld3(pos, i);
    f3 vji = f3sub(pj, pi);
    float nji2 = f3dot(vji, vji);
    float dist = sqrtf(nji2);
    int r0i = (i == 0) ? (NRES - 1) : (i - 1);
    int r1i = (i == NRES - 1) ? 0 : (i + 1);
    f3 vr0 = f3sub(ld3(pos, r0i), pi);
    f3 vr1 = f3sub(ld3(pos, r1i), pi);
    float nr02 = f3dot(vr0, vr0);

    float ct = f3dot(vji, vr0) * __builtin_amdgcn_rsqf(fmaxf(nji2 * nr02, 1e-30f));
    f3 p1 = f3cross(vr0, vr1);
    f3 p2 = f3cross(vr0, vji);
    float pa = f3dot(p1, p2);
    float pb = f3dot(f3cross(p1, p2), vr0) / (sqrtf(nr02) + 1e-7f);
    float cp = cos_atan2(pb, pa);

    f3 pni = ld3(posn, i), pci = ld3(posc, i);
    f3 o1x = f3sub(pni, pi);
    f3 o1z = f3cross(o1x, f3cross(o1x, f3sub(pci, pi)));
    float no1z2 = f3dot(o1z, o1z);
    float o1zl = sqrtf(no1z2) + 1e-7f;
    f3 pnj = ld3(posn, j), pcj = ld3(posc, j);
    f3 o2x = f3sub(pnj, pj);
    f3 o2z = f3cross(o2x, f3cross(o2x, f3sub(pcj, pj)));
    float no2z2 = f3dot(o2z, o2z);
    float o2zl = sqrtf(no2z2) + 1e-7f;
    f3 nv = f3cross(o1z, o2z);
    float y1 = f3dot(f3cross(o1x, nv), o1z) / o1zl;
    float ca1 = cos_atan2(y1, f3dot(o1x, nv));
    float ca2 = f3dot(o1z, o2z) * __builtin_amdgcn_rsqf(fmaxf(no1z2 * no2z2, 1e-30f));
    float y3 = f3dot(f3cross(nv, o2x), o2z) / o2zl;
    float ca3 = cos_atan2(y3, f3dot(nv, o2x));

    float u = fminf(dist * (1.0f/11.5f), 1.0f);
    float spu, cpu;
    __sincosf(PI_F * u, &spu, &cpu);
    float fc = 0.5f * (cpu + 1.0f);
    float pref = 0.41702882811414954f * __builtin_amdgcn_rcpf(dist + 1e-6f) * fc;
    float rb[6];
    {
      float twoc = 2.0f * cpu;
      float s_nm1 = 0.0f, s_n = spu;
      #pragma unroll
      for (int nn = 0; nn < 6; ++nn) {
        rb[nn] = pref * s_n;
        float s_np1 = twoc * s_n - s_nm1;
        s_nm1 = s_n; s_n = s_np1;
      }
    }

    float ctv[3] = {1.0f, ct, 2.0f*ct*ct - 1.0f};
    float cpv[3] = {1.0f, cp, 2.0f*cp*cp - 1.0f};
    #pragma unroll
    for (int nn = 0; nn < 6; ++nn)
      #pragma unroll
      for (int l = 0; l < 3; ++l)
        #pragma unroll
        for (int m = 0; m < 3; ++m)
          sF[e][nn*9 + l*3 + m] = f2bf(rb[nn] * ctv[l] * cpv[m]);

    float cas[3] = {ca1, ca2, ca3};
    #pragma unroll
    for (int t = 0; t < 3; ++t) {
      float c = cas[t];
      float cav[3] = {1.0f, c, 2.0f*c*c - 1.0f};
      #pragma unroll
      for (int nn = 0; nn < 6; ++nn)
        #pragma unroll
        for (int l = 0; l < 3; ++l)
          sF[e][54 + t*18 + nn*3 + l] = f2bf(rb[nn] * cav[l]);
    }

    const float FRQ[8] = {1.0f, 0.31622776601683794f, 0.1f, 0.03162277660168379f,
                          0.01f, 0.003162277660168379f, 0.001f, 0.0003162277660168379f};
    float dpe = (float)(j - i);
    #pragma unroll
    for (int q = 0; q < 8; ++q) {
      float s, c;
      __sincosf(dpe * FRQ[q], &s, &c);
      sF[e][108 + q] = f2bf(c);
      sF[e][116 + q] = f2bf(s);
    }
    sF[e][124] = 0; sF[e][125] = 0; sF[e][126] = 0; sF[e][127] = 0;
  } else {
    const int t2 = tid - 64;
    for (int it = 0; it < 6; ++it) {
      int idx = it * 192 + t2;
      if (idx < 1024) {
        int row = idx >> 4;
        int c8 = idx & 15;
        *(short8*)&sXJ[row][c8*8] = *(const short8*)&xb[(size_t)sJ[row] * 128 + c8*8];
      }
    }
  }
  __syncthreads();

  const int lane = tid & 63, w = tid >> 6;
  const int quad = lane >> 4, colb = lane & 15;
  const int nb = w * 2;

  short8 bE[4][2], bM[4][2];
  #pragma unroll
  for (int kt = 0; kt < 4; ++kt)
    #pragma unroll
    for (int nt = 0; nt < 2; ++nt) {
      bE[kt][nt] = *(const short8*)&Wef[(size_t)((kt*8 + nb + nt)*64 + lane)*8];
      bM[kt][nt] = *(const short8*)&Wmf[(size_t)((kt*8 + nb + nt)*64 + lane)*8];
    }

  floatx4 accE[4][2], accM[4][2];
  #pragma unroll
  for (int mt = 0; mt < 4; ++mt)
    #pragma unroll
    for (int nt = 0; nt < 2; ++nt) {
      accE[mt][nt] = (floatx4){0.f, 0.f, 0.f, 0.f};
      accM[mt][nt] = (floatx4){0.f, 0.f, 0.f, 0.f};
    }

  #pragma unroll
  for (int kt = 0; kt < 4; ++kt) {
    #pragma unroll
    for (int mt = 0; mt < 4; ++mt) {
      short8 af = *(const short8*)&sF [mt*16 + colb][kt*32 + quad*8];
      short8 ax = *(const short8*)&sXJ[mt*16 + colb][kt*32 + quad*8];
      #pragma unroll
      for (int nt = 0; nt < 2; ++nt) {
        accE[mt][nt] = __builtin_amdgcn_mfma_f32_16x16x32_bf16(af, bE[kt][nt], accE[mt][nt], 0, 0, 0);
        accM[mt][nt] = __builtin_amdgcn_mfma_f32_16x16x32_bf16(ax, bM[kt][nt], accM[mt][nt], 0, 0, 0);
      }
    }
  }
  __syncthreads();   // all LDS reads done; reuse sXJ as m-staging

  short (*sM)[136] = sXJ;
  #pragma unroll
  for (int mt = 0; mt < 4; ++mt)
    #pragma unroll
    for (int nt = 0; nt < 2; ++nt) {
      int ch = w*32 + nt*16 + colb;
      #pragma unroll
      for (int r = 0; r < 4; ++r) {
        int e = mt*16 + quad*4 + r;
        sM[e][ch] = f2bf(swish_fast(accM[mt][nt][r]) * swish_fast(accE[mt][nt][r]));
      }
    }
  __syncthreads();

  #pragma unroll
  for (int it = 0; it < 16; ++it) {
    int flat = it * 256 + tid;        // 0..4095
    int row = flat >> 6, p = flat & 63;
    bf16x2 v = *(const bf16x2*)&sM[row][p*2];
    atom_pk_bf16(&aggb[(size_t)sI[row] * 128 + p*2], v);
  }
}

// ---------------------------------------------------------------------------
// fused update + both heads (MFMA). 64 nodes/block, 256 threads = 4 waves.
__global__ __launch_bounds__(256) void k_upd(
    const short* __restrict__ xb, const short* __restrict__ aggb,
    const short* __restrict__ Wuf, const short* __restrict__ Wo0f,
    const short* __restrict__ Wn0f, const short* __restrict__ Wo1f,
    const float* __restrict__ bn0, const float* __restrict__ Wnf,
    const float* __restrict__ bnf, const float* __restrict__ bo0,
    const float* __restrict__ bo1, const float* __restrict__ Wof,
    const float* __restrict__ bof, float* __restrict__ out0,
    float* __restrict__ out1)
{
  __shared__ __align__(16) short sA[64][136];   // aggb -> xe bf16
  __shared__ __align__(16) short sX[64][136];   // xb   -> h  bf16
  __shared__ float sS[64][33];                  // hn / h2 scratch (f32)

  const int tid = threadIdx.x;
  const int lane = tid & 63, w = tid >> 6;
  const int quad = lane >> 4, colb = lane & 15;
  const int n0 = blockIdx.x * 64;

  #pragma unroll
  for (int it = 0; it < 4; ++it) {
    int idx = it * 256 + tid;        // 0..1023
    int row = idx >> 4, c8 = idx & 15;
    int n = n0 + row;
    short8 va = (short8)(short)0, vx = (short8)(short)0;
    if (n < NRES) {
      va = *(const short8*)&aggb[(size_t)n * 128 + c8*8];
      vx = *(const short8*)&xb  [(size_t)n * 128 + c8*8];
    }
    *(short8*)&sA[row][c8*8] = va;
    *(short8*)&sX[row][c8*8] = vx;
  }
  __syncthreads();

  // hn = relu(x@Wn0+bn0); wave w handles mtile w
  {
    floatx4 accN[2];
    accN[0] = (floatx4){0.f,0.f,0.f,0.f}; accN[1] = (floatx4){0.f,0.f,0.f,0.f};
    #pragma unroll
    for (int kt = 0; kt < 4; ++kt) {
      short8 a = *(const short8*)&sX[w*16 + colb][kt*32 + quad*8];
      #pragma unroll
      for (int nt = 0; nt < 2; ++nt) {
        short8 bf = *(const short8*)&Wn0f[(size_t)((kt*2 + nt)*64 + lane)*8];
        accN[nt] = __builtin_amdgcn_mfma_f32_16x16x32_bf16(a, bf, accN[nt], 0, 0, 0);
      }
    }
    #pragma unroll
    for (int nt = 0; nt < 2; ++nt) {
      int col = nt*16 + colb;
      float bias = bn0[col];
      #pragma unroll
      for (int r = 0; r < 4; ++r)
        sS[w*16 + quad*4 + r][col] = fmaxf(accN[nt][r] + bias, 0.0f);
    }
  }
  __syncthreads();
  if (tid < 128) {
    int row = tid >> 1, oc = tid & 1;
    int n = n0 + row;
    if (n < NRES) {
      float a2 = bnf[oc];
      #pragma unroll
      for (int k = 0; k < 32; ++k) a2 += sS[row][k] * Wnf[k*2 + oc];
      out1[(size_t)n * 2 + oc] = a2;
    }
  }

  // GEMM1: t = agg@Wu
  floatx4 acc1[4][2];
  #pragma unroll
  for (int mt = 0; mt < 4; ++mt) {
    acc1[mt][0] = (floatx4){0.f,0.f,0.f,0.f};
    acc1[mt][1] = (floatx4){0.f,0.f,0.f,0.f};
  }
  #pragma unroll
  for (int kt = 0; kt < 4; ++kt) {
    short8 b0 = *(const short8*)&Wuf[(size_t)((kt*8 + w*2 + 0)*64 + lane)*8];
    short8 b1 = *(const short8*)&Wuf[(size_t)((kt*8 + w*2 + 1)*64 + lane)*8];
    #pragma unroll
    for (int mt = 0; mt < 4; ++mt) {
      short8 a = *(const short8*)&sA[mt*16 + colb][kt*32 + quad*8];
      acc1[mt][0] = __builtin_amdgcn_mfma_f32_16x16x32_bf16(a, b0, acc1[mt][0], 0, 0, 0);
      acc1[mt][1] = __builtin_amdgcn_mfma_f32_16x16x32_bf16(a, b1, acc1[mt][1], 0, 0, 0);
    }
  }
  __syncthreads();
  // xe = x + swish(t): additive x term read from sX (bf16 x tile, still intact)
  #pragma unroll
  for (int mt = 0; mt < 4; ++mt)
    #pragma unroll
    for (int nt = 0; nt < 2; ++nt)
      #pragma unroll
      for (int r = 0; r < 4; ++r) {
        int row = mt*16 + quad*4 + r, col = w*32 + nt*16 + colb;
        float xv = bf2f(sX[row][col]);
        sA[row][col] = f2bf(xv + swish_fast(acc1[mt][nt][r]));
      }
  __syncthreads();

  // GEMM2: h = relu(xe@Wo0 + bo0)
  floatx4 acc2[4][2];
  #pragma unroll
  for (int mt = 0; mt < 4; ++mt) {
    acc2[mt][0] = (floatx4){0.f,0.f,0.f,0.f};
    acc2[mt][1] = (floatx4){0.f,0.f,0.f,0.f};
  }
  #pragma unroll
  for (int kt = 0; kt < 4; ++kt) {
    short8 b0 = *(const short8*)&Wo0f[(size_t)((kt*8 + w*2 + 0)*64 + lane)*8];
    short8 b1 = *(const short8*)&Wo0f[(size_t)((kt*8 + w*2 + 1)*64 + lane)*8];
    #pragma unroll
    for (int mt = 0; mt < 4; ++mt) {
      short8 a = *(const short8*)&sA[mt*16 + colb][kt*32 + quad*8];
      acc2[mt][0] = __builtin_amdgcn_mfma_f32_16x16x32_bf16(a, b0, acc2[mt][0], 0, 0, 0);
      acc2[mt][1] = __builtin_amdgcn_mfma_f32_16x16x32_bf16(a, b1, acc2[mt][1], 0, 0, 0);
    }
  }
  __syncthreads();
  #pragma unroll
  for (int mt = 0; mt < 4; ++mt)
    #pragma unroll
    for (int nt = 0; nt < 2; ++nt) {
      int col = w*32 + nt*16 + colb;
      float bias = bo0[col];
      #pragma unroll
      for (int r = 0; r < 4; ++r) {
        int row = mt*16 + quad*4 + r;
        sX[row][col] = f2bf(fmaxf(acc2[mt][nt][r] + bias, 0.0f));
      }
    }
  __syncthreads();

  // GEMM3: h2 = relu(h@Wo1 + bo1); wave w handles mtile w
  {
    floatx4 accH[2];
    accH[0] = (floatx4){0.f,0.f,0.f,0.f}; accH[1] = (floatx4){0.f,0.f,0.f,0.f};
    #pragma unroll
    for (int kt = 0; kt < 4; ++kt) {
      short8 a = *(const short8*)&sX[w*16 + colb][kt*32 + quad*8];
      #pragma unroll
      for (int nt = 0; nt < 2; ++nt) {
        short8 bf = *(const short8*)&Wo1f[(size_t)((kt*2 + nt)*64 + lane)*8];
        accH[nt] = __builtin_amdgcn_mfma_f32_16x16x32_bf16(a, bf, accH[nt], 0, 0, 0);
      }
    }
    __syncthreads();
    #pragma unroll
    for (int nt = 0; nt < 2; ++nt) {
      int col = nt*16 + colb;
      float bias = bo1[col];
      #pragma unroll
      for (int r = 0; r < 4; ++r)
        sS[w*16 + quad*4 + r][col] = fmaxf(accH[nt][r] + bias, 0.0f);
    }
  }
  __syncthreads();

  if (tid < 64) {
    int n = n0 + tid;
    if (n < NRES) {
      float a2 = bof[0];
      #pragma unroll
      for (int k = 0; k < 32; ++k) a2 += sS[tid][k] * Wof[k];
      out0[n] = 1.0f / (1.0f + expf(-a2));
    }
  }
}

// ---------------------------------------------------------------------------
extern "C" void kernel_launch(void* const* d_in, const int* in_sizes, int n_in,
                              void* d_out, int out_size, void* d_ws, size_t ws_size,
                              hipStream_t stream) {
  (void)in_sizes; (void)n_in; (void)out_size; (void)ws_size;
  const int*   z     = (const int*)  d_in[0];
  const float* pos   = (const float*)d_in[1];
  const float* posn  = (const float*)d_in[2];
  const float* posc  = (const float*)d_in[3];
  const float* bb    = (const float*)d_in[4];
  const float* side  = (const float*)d_in[5];
  const float* esm   = (const float*)d_in[6];
  const int*   ei    = (const int*)  d_in[8];
  const float* W_emb = (const float*)d_in[9];
  const float* b_emb = (const float*)d_in[10];
  const float* W_esm = (const float*)d_in[11];
  const float* b_esm = (const float*)d_in[12];
  const float* W_edge= (const float*)d_in[13];
  const float* W_msg = (const float*)d_in[14];
  const float* W_upd = (const float*)d_in[15];
  const float* W_o0  = (const float*)d_in[16];
  const float* b_o0  = (const float*)d_in[17];
  const float* W_o1  = (const float*)d_in[18];
  const float* b_o1  = (const float*)d_in[19];
  const float* W_of  = (const float*)d_in[20];
  const float* b_of  = (const float*)d_in[21];
  const float* W_n0  = (const float*)d_in[22];
  const float* b_n0  = (const float*)d_in[23];
  const float* W_nf  = (const float*)d_in[24];
  const float* b_nf  = (const float*)d_in[25];

  char* ws = (char*)d_ws;
  short* xb   = (short*)ws;                            // 12,800,000 B
  short* aggb = (short*)(ws + 12800000);               // 12,800,000 B
  short* Wef  = (short*)(ws + 25600000);               // 32,768 B
  short* Wmf  = (short*)(ws + 25632768);               // 32,768 B
  short* Wsf  = (short*)(ws + 25665536);               // 163,840 B
  short* Wuf  = (short*)(ws + 25829376);               // 32,768 B
  short* Wo0f = (short*)(ws + 25862144);               // 32,768 B
  short* Wn0f = (short*)(ws + 25894912);               // 8,192 B
  short* Wo1f = (short*)(ws + 25903104);               // 8,192 B
  float* out0 = (float*)d_out;                         // [N]
  float* out1 = out0 + NRES;                           // [N,2]

  hipMemsetAsync(aggb, 0, (size_t)NRES * 128 * sizeof(short), stream);

  k_wprep<<<608, 256, 0, stream>>>(W_edge, W_msg, W_esm, W_upd, W_o0, W_n0, W_o1,
                                   Wef, Wmf, Wsf, Wuf, Wo0f, Wn0f, Wo1f);
  k_xa   <<<12500, 256, 0, stream>>>(z, bb, side, W_emb, b_emb, xb);
  k_esm  <<<782,   256, 0, stream>>>(esm, Wsf, b_esm, xb);
  k_edge <<<15625, 256, 0, stream>>>(ei, pos, posn, posc, xb, Wef, Wmf, aggb);
  k_upd  <<<782,   256, 0, stream>>>(xb, aggb, Wuf, Wo0f, Wn0f, Wo1f,
                                     b_n0, W_nf, b_nf, b_o0, b_o1, W_of, b_of,
                                     out0, out1);
}